// Round 1
// 1281.278 us; speedup vs baseline: 1.0226x; 1.0226x over previous
//
#include <hip/hip_runtime.h>

typedef __bf16 bf16;
typedef __bf16 bf16x8 __attribute__((ext_vector_type(8)));
typedef __bf16 bf16x4 __attribute__((ext_vector_type(4)));
typedef float f32x4 __attribute__((ext_vector_type(4)));

typedef __attribute__((address_space(3))) void lds_void_t;
typedef const __attribute__((address_space(1))) void gbl_void_t;

#define TOK 4096
#define KBROWS 5120

enum { M_BF16 = 0, M_F32 = 1, M_RELU = 2, M_QKV = 3, M_SCOREXP = 4, M_PV = 5 };

struct GemmArgs {
  const bf16* A; long long sAe, sAi; int ldA;
  const bf16* B; long long sBe, sBi; int ldB;
  const bf16* B2; long long sB2e; int ldB2;
  bf16* C; float* Cf; long long sCe, sCi; int ldC;
  int M, N, K, iPerE;
  bf16 *quv, *kbuf, *vt;
  const float *uvA, *uvB;
  float scale;
};

// ---------------- GEMM: C = A @ B^T, A (MxK) row-major, B (NxK) row-major ----------------
// Staging via global_load_lds; lane (8r+c) fetches chunk c^r -> XOR-swizzled LDS, frag reads
// sw=(4s+quad)^l7 are 0-bank-conflict. M_SCOREXP: epilogue exp (bounded logits, mask->0).
// M_PV: A-frags cover each P row's full K exactly once -> row-sum l computed in-loop, /l in epi.
template<int MODE, bool SPLITB, int TM, int TN>
__global__ __launch_bounds__(256, 4)
void gemm_kernel(GemmArgs g) {
  constexpr int FA = TM / 32, FB = TN / 32;
  int z = blockIdx.z;
  int e = z / g.iPerE;
  int i = z % g.iPerE;
  const bf16* A = g.A + e * g.sAe + i * g.sAi;
  const bf16* B = g.B + e * g.sBe + i * g.sBi;
  const bf16* B2 = nullptr;
  if constexpr (SPLITB) B2 = g.B2 + e * g.sB2e;

  int tm = blockIdx.x * TM;
  int tn = blockIdx.y * TN;

  __shared__ uint4 As4[TM * 8];
  __shared__ uint4 Bs4[TN * 8];
  __shared__ float ls[MODE == M_PV ? TM : 1];
  bf16* As_lds = (bf16*)As4;
  bf16* Bs_lds = (bf16*)Bs4;

  int tid = threadIdx.x;
  int wave = tid >> 6, lane = tid & 63;
  int wm = (wave >> 1) * (TM / 2), wn = (wave & 1) * (TN / 2);
  int quad = lane >> 4, l15 = lane & 15;
  int l7 = l15 & 7;
  int l8r = lane >> 3, l8c = lane & 7;
  int fc = l8c ^ l8r;

  f32x4 acc[FA][FB] = {};
  float lreg[FA];
#pragma unroll
  for (int t = 0; t < FA; ++t) lreg[t] = 0.f;

  for (int k0 = 0; k0 < g.K; k0 += 64) {
#pragma unroll
    for (int ii = 0; ii < FA; ++ii) {
      int rowbase = (wave * FA + ii) * 8;
      int r = rowbase + l8r;
      const bf16* gp = &A[(long long)(tm + r) * g.ldA + k0 + fc * 8];
      __builtin_amdgcn_global_load_lds((gbl_void_t*)gp, (lds_void_t*)&As_lds[rowbase * 64], 16, 0, 0);
    }
#pragma unroll
    for (int ii = 0; ii < FB; ++ii) {
      int rowbase = (wave * FB + ii) * 8;
      int r = rowbase + l8r;
      const bf16* gp;
      if constexpr (SPLITB) {
        int kk = k0 + fc * 8;
        gp = (kk < 512) ? &B[(long long)(tn + r) * g.ldB + kk]
                        : &B2[(long long)(tn + r) * g.ldB2 + (kk - 512)];
      } else {
        gp = &B[(long long)(tn + r) * g.ldB + k0 + fc * 8];
      }
      __builtin_amdgcn_global_load_lds((gbl_void_t*)gp, (lds_void_t*)&Bs_lds[rowbase * 64], 16, 0, 0);
    }
    __syncthreads();
#pragma unroll
    for (int s = 0; s < 2; ++s) {
      int sw = (s * 4 + quad) ^ l7;
      bf16x8 af[FA], bfr[FB];
#pragma unroll
      for (int t = 0; t < FA; ++t) af[t]  = ((const bf16x8*)As4)[(wm + t * 16 + l15) * 8 + sw];
#pragma unroll
      for (int t = 0; t < FB; ++t) bfr[t] = ((const bf16x8*)Bs4)[(wn + t * 16 + l15) * 8 + sw];
      if constexpr (MODE == M_PV) {
#pragma unroll
        for (int t = 0; t < FA; ++t)
#pragma unroll
          for (int q2 = 0; q2 < 8; ++q2) lreg[t] += (float)af[t][q2];
      }
#pragma unroll
      for (int a = 0; a < FA; ++a)
#pragma unroll
        for (int b = 0; b < FB; ++b)
          acc[a][b] = __builtin_amdgcn_mfma_f32_16x16x32_bf16(af[a], bfr[b], acc[a][b], 0, 0, 0);
    }
    __syncthreads();
  }

  if constexpr (MODE == M_PV) {
    // rowsum l: lane holds partial of row (wm + t*16 + l15); reduce across quads
#pragma unroll
    for (int t = 0; t < FA; ++t) {
      lreg[t] += __shfl_xor(lreg[t], 16);
      lreg[t] += __shfl_xor(lreg[t], 32);
      if (quad == 0) ls[wm + t * 16 + l15] = lreg[t];
    }
    __syncthreads();
  }

  // epilogues. C/D layout: col = lane&15, row = quad*4 + reg (m89-verified)
  if constexpr (MODE == M_QKV) {
    const float* uv = e ? g.uvB : g.uvA;
#pragma unroll
    for (int a = 0; a < FA; ++a) {
      int mB = tm + wm + a * 16 + quad * 4;
#pragma unroll
      for (int b = 0; b < FB; ++b) {
        int col = tn + wn + b * 16 + l15;
        int region = col >> 9, cin = col & 511;
        float u0 = 0.f, v0 = 0.f;
        if (region == 0) { u0 = uv[cin]; v0 = uv[512 + cin]; }
#pragma unroll
        for (int r = 0; r < 4; ++r) {
          int m = mB + r;
          float val = acc[a][b][r];
          if (region == 0) {
            long long qb = (long long)e * TOK * 1024 + (long long)m * 1024;
            g.quv[qb + cin]       = (bf16)(val + u0);
            g.quv[qb + 512 + cin] = (bf16)(val + v0);
          } else if (region == 1) {
            g.kbuf[(long long)e * KBROWS * 512 + (long long)(1024 + m) * 512 + cin] = (bf16)val;
          } else {  // region 2: S@Wvo -> vwoT[od][1024+token] (transposed scatter)
            g.vt[(long long)e * 512 * KBROWS + (long long)cin * KBROWS + 1024 + m] = (bf16)val;
          }
        }
      }
    }
  } else if constexpr (MODE == M_SCOREXP) {
    bf16* C = g.C + e * g.sCe + i * g.sCi;
    int T = 1024 - ((i < 2 ? i : 2) << 9);   // mask cols < T
#pragma unroll
    for (int a = 0; a < FA; ++a) {
      int mB = tm + wm + a * 16 + quad * 4;
#pragma unroll
      for (int b = 0; b < FB; ++b) {
        int col = tn + wn + b * 16 + l15;
        float bias = (col < T) ? -1e9f : 0.0f;
#pragma unroll
        for (int r = 0; r < 4; ++r)
          C[(long long)(mB + r) * g.ldC + col] = (bf16)__expf(acc[a][b][r] * g.scale + bias);
      }
    }
  } else if constexpr (MODE == M_PV) {
    float* Cf = g.Cf + e * g.sCe + i * g.sCi;
#pragma unroll
    for (int a = 0; a < FA; ++a) {
      int lrow = wm + a * 16 + quad * 4;
      int mB = tm + lrow;
#pragma unroll
      for (int b = 0; b < FB; ++b) {
        int col = tn + wn + b * 16 + l15;
#pragma unroll
        for (int r = 0; r < 4; ++r)
          Cf[(long long)(mB + r) * g.ldC + col] = acc[a][b][r] / ls[lrow + r];
      }
    }
  } else {
#pragma unroll
    for (int a = 0; a < FA; ++a) {
      int mB = tm + wm + a * 16 + quad * 4;
#pragma unroll
      for (int b = 0; b < FB; ++b) {
        int col = tn + wn + b * 16 + l15;
#pragma unroll
        for (int r = 0; r < 4; ++r) {
          float val = acc[a][b][r];
          if constexpr (MODE == M_RELU) val = val > 0.f ? val : 0.f;
          if constexpr (MODE == M_F32) {
            float* Cf = g.Cf + e * g.sCe + i * g.sCi;
            Cf[(long long)(mB + r) * g.ldC + col] = val;
          } else {
            bf16* C = g.C + e * g.sCe + i * g.sCi;
            C[(long long)(mB + r) * g.ldC + col] = (bf16)val;
          }
        }
      }
    }
  }
}

// ---------------- unified weight prep: all transposes + Wv plain cast, one dispatch ----------------
// Vectorized: float4 global reads, bf16x8 (16B) global writes. Transpose goes through an
// XOR-swizzled LDS tile (pitch 68, col ^= ((row>>4)&3)<<2):
//   phase-1 scalar bf16 writes land 2 lanes/bank (free), phase-2 8B reads are conflict-free.
__global__ __launch_bounds__(256)
void prep_weights(const float* qa, const float* qb, const float* oa, const float* ob,
                  const float* w1a, const float* w1b, const float* w2a, const float* w2b,
                  bf16* wqkvT, bf16* wrT, bf16* wvPlain, bf16* woT, bf16* w1T, bf16* w2T) {
  int id = blockIdx.x;
  const float* src; bf16* dst; int R, C, tx, ty; bool plain = false;
  if (id < 3072) {          // Wqkvr: 48 mats x 64 tiles
    int mat = id >> 6, tile = id & 63;
    tx = tile & 7; ty = tile >> 3;
    int e = mat / 24, rj = mat % 24, j = rj >> 2, c = rj & 3;
    src = (e ? qb : qa) + (long long)(j * 4 + c) * 262144;
    R = 512; C = 512;
    if (c < 2)        dst = wqkvT + ((long long)(e * 6 + j) * 3 + c) * 262144;
    else if (c == 2) { dst = wvPlain + (long long)(e * 6 + j) * 262144; plain = true; }
    else              dst = wrT + (long long)(e * 6 + j) * 262144;
  } else if (id < 3840) {   // Wo: 12 mats x 64 tiles
    int id2 = id - 3072; int mat = id2 >> 6, tile = id2 & 63;
    tx = tile & 7; ty = tile >> 3;
    int e = mat / 6, j = mat % 6;
    src = (e ? ob : oa) + (long long)j * 262144;
    dst = woT + (long long)mat * 262144; R = 512; C = 512;
  } else if (id < 6912) {   // W1 (512x2048): 12 mats x 256 tiles
    int id2 = id - 3840; int mat = id2 >> 8, tile = id2 & 255;
    tx = tile & 31; ty = tile >> 5;
    int e = mat / 6, j = mat % 6;
    src = (e ? w1b : w1a) + (long long)j * 512 * 2048;
    dst = w1T + (long long)mat * 512 * 2048; R = 512; C = 2048;
  } else {                  // W2 (2048x512): 12 mats x 256 tiles
    int id2 = id - 6912; int mat = id2 >> 8, tile = id2 & 255;
    tx = tile & 7; ty = tile >> 3;
    int e = mat / 6, j = mat % 6;
    src = (e ? w2b : w2a) + (long long)j * 2048 * 512;
    dst = w2T + (long long)mat * 2048 * 512; R = 2048; C = 512;
  }
  int c0 = tx * 64, r0 = ty * 64;
  int tid = threadIdx.x;

  if (plain) {
    // pure cast: 2x float4 read -> one 16B bf16x8 store, 1KB/wave-instr both directions
    int c8 = (tid & 7) * 8;
    int r8 = tid >> 3;                       // 0..31
#pragma unroll
    for (int rep = 0; rep < 2; ++rep) {
      int rr = r8 + rep * 32;
      const float* sp = &src[(long long)(r0 + rr) * C + c0 + c8];
      float4 f0 = *(const float4*)sp;
      float4 f1 = *(const float4*)(sp + 4);
      bf16 o[8] __attribute__((aligned(16))) =
        {(bf16)f0.x, (bf16)f0.y, (bf16)f0.z, (bf16)f0.w,
         (bf16)f1.x, (bf16)f1.y, (bf16)f1.z, (bf16)f1.w};
      *(bf16x8*)&dst[(long long)(r0 + rr) * C + c0 + c8] = *(const bf16x8*)o;
    }
  } else {
    // transpose via swizzled LDS: t_logical[srcCol][srcRow], pitch 68,
    // physical col = logicalCol ^ (((row>>4)&3)<<2)
    __shared__ bf16 t[64 * 68];
    int l15 = tid & 15;                      // src-col group
    int hi  = tid >> 4;                      // 0..15 src-row
    int cc = l15 * 4;
#pragma unroll
    for (int rep = 0; rep < 4; ++rep) {
      int rr = hi + rep * 16;
      float4 f = *(const float4*)&src[(long long)(r0 + rr) * C + c0 + cc];
      float v[4] = {f.x, f.y, f.z, f.w};
#pragma unroll
      for (int i2 = 0; i2 < 4; ++i2) {
        int row = cc + i2;
        int col = rr ^ (((row >> 4) & 3) << 2);
        t[row * 68 + col] = (bf16)v[i2];
      }
    }
    __syncthreads();
    int oc = tid >> 2;                       // output row (src col) 0..63
    int kk = tid & 3;                        // 16-elem chunk
    bf16 outv[16] __attribute__((aligned(16)));
#pragma unroll
    for (int u = 0; u < 4; ++u) {
      int col = (16 * kk + 4 * u) ^ (((oc >> 4) & 3) << 2);
      *(bf16x4*)&outv[u * 4] = *(const bf16x4*)&t[oc * 68 + col];
    }
    bf16* dp = &dst[(long long)(c0 + oc) * R + r0 + 16 * kk];
    *(bf16x8*)dp       = *(const bf16x8*)&outv[0];
    *(bf16x8*)(dp + 8) = *(const bf16x8*)&outv[8];
  }
}

// ---------------- misc setup kernels ----------------
__global__ __launch_bounds__(256)
void sinusoid_kernel(bf16* rb) {
  int i = blockIdx.x, m = threadIdx.x;
  float p = (float)(1535 - i);
  float inv = expf(-((float)(2 * m) * (1.0f / 512.0f)) * 9.210340371976184f);
  float ang = p * inv;
  rb[(long long)i * 512 + 2 * m]     = (bf16)sinf(ang);
  rb[(long long)i * 512 + 2 * m + 1] = (bf16)cosf(ang);
}

__global__ __launch_bounds__(128)
void embed_kernel(const int* src, const float* emb, bf16* Sb, float* Sf) {
  int row = blockIdx.x, e = blockIdx.y, tid = threadIdx.x;
  int tok = e ? src[4095 - row] : src[row];
  long long base = ((long long)e * TOK + row) * 512 + tid * 4;
  float4 f = *(const float4*)&emb[(long long)tok * 512 + tid * 4];
  *(float4*)&Sf[base] = f;
  Sb[base + 0] = (bf16)f.x; Sb[base + 1] = (bf16)f.y;
  Sb[base + 2] = (bf16)f.z; Sb[base + 3] = (bf16)f.w;
}

// zero the "no-memory" regions: kbuf rows 0..1023, vwoT cols 0..1023
__global__ __launch_bounds__(256)
void zero_kv(bf16* kbuf, bf16* vwoT) {
  int r = blockIdx.x, e = blockIdx.y, which = blockIdx.z, tid = threadIdx.x;
  if (which == 0) {
    bf16* p = kbuf + ((long long)e * KBROWS + r) * 512;
    p[tid] = (bf16)0.f; p[tid + 256] = (bf16)0.f;
  } else if (r < 512) {
    bf16* p = vwoT + ((long long)e * 512 + r) * KBROWS;
#pragma unroll
    for (int k = 0; k < 4; ++k) p[tid + k * 256] = (bf16)0.f;
  }
}

// ---------------- residual + layernorm; outMode 1 = write final output directly ----------------
__global__ __launch_bounds__(64)
void ln_kernel(const float* Xf, const float* Tf, const float* lnA, const float* lnB,
               int gOff, bf16* OutB, float* OutF, int outMode, float* finalOut) {
  int row = blockIdx.x, e = blockIdx.y;
  long long base = ((long long)e * TOK + row) * 512;
  const float* x = Xf + base;
  const float* t = Tf + base;
  const float* ln = e ? lnB : lnA;
  const float* gm = ln + gOff;
  const float* bt = ln + gOff + 512;
  int lane = threadIdx.x;
  float vals[8];
  float s = 0.f;
#pragma unroll
  for (int k = 0; k < 8; ++k) { int d = lane + k * 64; vals[k] = x[d] + t[d]; s += vals[k]; }
  for (int off = 32; off; off >>= 1) s += __shfl_xor(s, off);
  float mu = s * (1.0f / 512.0f);
  float vs = 0.f;
#pragma unroll
  for (int k = 0; k < 8; ++k) { float d0 = vals[k] - mu; vs += d0 * d0; }
  for (int off = 32; off; off >>= 1) vs += __shfl_xor(vs, off);
  float rstd = rsqrtf(vs * (1.0f / 512.0f) + 1e-5f);
  if (outMode == 0) {
#pragma unroll
    for (int k = 0; k < 8; ++k) {
      int d = lane + k * 64;
      float y = (vals[k] - mu) * rstd * gm[d] + bt[d];
      OutB[base + d] = (bf16)y;
      OutF[base + d] = y;
    }
  } else {
    long long ob = e ? ((long long)(4095 - row) * 1024 + 512) : ((long long)row * 1024);
#pragma unroll
    for (int k = 0; k < 8; ++k) {
      int d = lane + k * 64;
      finalOut[ob + d] = (vals[k] - mu) * rstd * gm[d] + bt[d];
    }
  }
}

extern "C" void kernel_launch(void* const* d_in, const int* in_sizes, int n_in,
                              void* d_out, int out_size, void* d_ws, size_t ws_size,
                              hipStream_t stream) {
  const int*   src   = (const int*)d_in[0];
  const float* emb   = (const float*)d_in[2];
  const float* Wq_a  = (const float*)d_in[3];
  const float* Wo_a  = (const float*)d_in[4];
  const float* W1_a  = (const float*)d_in[5];
  const float* W2_a  = (const float*)d_in[6];
  const float* ln_a  = (const float*)d_in[7];
  const float* uv_a  = (const float*)d_in[8];
  const float* Wq_b  = (const float*)d_in[9];
  const float* Wo_b  = (const float*)d_in[10];
  const float* W1_b  = (const float*)d_in[11];
  const float* W2_b  = (const float*)d_in[12];
  const float* ln_b  = (const float*)d_in[13];
  const float* uv_b  = (const float*)d_in[14];
  float* out = (float*)d_out;

  char* w = (char*)d_ws;
  size_t off = 0;
  auto alloc = [&](long long elems, int esz) -> char* {
    char* p = w + off;
    off += (size_t)elems * esz;
    off = (off + 255) & ~(size_t)255;
    return p;
  };
  bf16* wqkvT = (bf16*)alloc(2LL * 6 * 1536 * 512, 2);  // rows: q, k, (wvo = Wv@Wo set at runtime)
  bf16* woT   = (bf16*)alloc(2LL * 6 * 512 * 512, 2);
  bf16* w1T   = (bf16*)alloc(2LL * 6 * 2048 * 512, 2);
  bf16* w2T   = (bf16*)alloc(2LL * 6 * 512 * 2048, 2);
  bf16* pk    = (bf16*)alloc(2LL * 6 * 1536 * 512, 2);
  bf16* Sb    = (bf16*)alloc(2LL * TOK * 512, 2);
  float* Sf   = (float*)alloc(2LL * TOK * 512, 4);
  bf16* quv   = (bf16*)alloc(2LL * TOK * 1024, 2);
  bf16* kbuf  = (bf16*)alloc(2LL * KBROWS * 512, 2);
  bf16* vwoT  = (bf16*)alloc(2LL * 512 * KBROWS, 2);
  bf16* P     = (bf16*)alloc(2LL * 8 * 512 * 1536, 2);
  float* t1f  = (float*)alloc(2LL * TOK * 512, 4);
  bf16* f1    = (bf16*)alloc(2LL * TOK * 2048, 2);
  // overlays (setup-only, inside f1's region; f1 first written in layer loop):
  bf16* rb      = f1;                          // 1.5 MB
  bf16* wrT     = f1 + 1024LL * 1024;          // 6 MB at +2MB
  bf16* wvPlain = f1 + 4096LL * 1024;          // 6 MB at +8MB

  if (off > ws_size) return;

  // ---- setup ----
  prep_weights<<<9984, 256, 0, stream>>>(Wq_a, Wq_b, Wo_a, Wo_b, W1_a, W1_b, W2_a, W2_b,
                                         wqkvT, wrT, wvPlain, woT, w1T, w2T);
  sinusoid_kernel<<<1536, 256, 0, stream>>>(rb);
  embed_kernel<<<dim3(4096, 2), 128, 0, stream>>>(src, emb, Sb, Sf);
  zero_kv<<<dim3(1024, 2, 2), 256, 0, stream>>>(kbuf, vwoT);

  {  // pk[e][j] = R @ Wr[e][j]
    GemmArgs g = {};
    g.A = rb; g.sAe = 0; g.sAi = 0; g.ldA = 512;
    g.B = wrT; g.sBe = 0; g.sBi = 512LL * 512; g.ldB = 512;
    g.C = pk; g.sCe = 0; g.sCi = 1536LL * 512; g.ldC = 512;
    g.M = 1536; g.N = 512; g.K = 512; g.iPerE = 12;
    gemm_kernel<M_BF16, false, 128, 128><<<dim3(12, 4, 12), 256, 0, stream>>>(g);
  }
  {  // wvoT[e][j][od][k] = Wvo[k][od] = sum_v Wv[k][v] Wo[v][od]  -> wqkvT slot 2
    GemmArgs g = {};
    g.A = woT; g.sAe = 6LL * 262144; g.sAi = 262144; g.ldA = 512;       // A[od][v] = Wo[v][od]
    g.B = wvPlain; g.sBe = 6LL * 262144; g.sBi = 262144; g.ldB = 512;   // B[k][v]  = Wv[k][v]
    g.C = wqkvT + 2LL * 262144; g.sCe = 18LL * 262144; g.sCi = 3LL * 262144; g.ldC = 512;
    g.M = 512; g.N = 512; g.K = 512; g.iPerE = 6;
    gemm_kernel<M_BF16, false, 128, 128><<<dim3(4, 4, 12), 256, 0, stream>>>(g);
  }

  const float scale = 0.044194173824159216f;  // 1/sqrt(512)

  for (int j = 0; j < 6; ++j) {
    {  // QKV: q+u/q+v -> quv, k -> kbuf(+1024), S@Wvo -> vwoT(+1024, transposed)
      GemmArgs g = {};
      g.A = Sb; g.sAe = (long long)TOK * 512; g.sAi = 0; g.ldA = 512;
      g.B = wqkvT + (long long)j * 1536 * 512; g.sBe = 6LL * 1536 * 512; g.sBi = 0; g.ldB = 512;
      g.M = TOK; g.N = 1536; g.K = 512; g.iPerE = 1;
      g.quv = quv; g.kbuf = kbuf; g.vt = vwoT; g.uvA = uv_a; g.uvB = uv_b;
      gemm_kernel<M_QKV, false, 128, 128><<<dim3(32, 12, 2), 256, 0, stream>>>(g);
    }
    {  // P = exp(qu@Kwin^T + qv@pk^T scaled+masked)  (no-max softmax numerator)
      GemmArgs g = {};
      g.A = quv; g.sAe = (long long)TOK * 1024; g.sAi = 512LL * 1024; g.ldA = 1024;
      g.B = kbuf; g.sBe = (long long)KBROWS * 512; g.sBi = 512LL * 512; g.ldB = 512;
      g.B2 = pk + (long long)j * 1536 * 512; g.sB2e = 6LL * 1536 * 512; g.ldB2 = 512;
      g.C = P; g.sCe = 8LL * 512 * 1536; g.sCi = 512LL * 1536; g.ldC = 1536;
      g.M = 512; g.N = 1536; g.K = 1024; g.iPerE = 8;
      g.scale = scale;
      gemm_kernel<M_SCOREXP, true, 128, 128><<<dim3(4, 12, 16), 256, 0, stream>>>(g);
    }
    {  // attn_proj = (P @ VWowin) / rowsum(P)  -> fp32 t1f
      GemmArgs g = {};
      g.A = P; g.sAe = 8LL * 512 * 1536; g.sAi = 512LL * 1536; g.ldA = 1536;
      g.B = vwoT; g.sBe = 512LL * KBROWS; g.sBi = 512; g.ldB = KBROWS;
      g.Cf = t1f; g.sCe = (long long)TOK * 512; g.sCi = 512LL * 512; g.ldC = 512;
      g.M = 512; g.N = 512; g.K = 1536; g.iPerE = 8;
      gemm_kernel<M_PV, false, 64, 128><<<dim3(8, 4, 16), 256, 0, stream>>>(g);
    }
    // H = LN(state + attn_out) — in-place into Sb/Sf
    ln_kernel<<<dim3(4096, 2), 64, 0, stream>>>(Sf, t1f, ln_a, ln_b, (j * 4 + 0) * 512, Sb, Sf, 0, out);
    {  // F1 = relu(H @ W1)
      GemmArgs g = {};
      g.A = Sb; g.sAe = (long long)TOK * 512; g.sAi = 0; g.ldA = 512;
      g.B = w1T + (long long)j * 2048 * 512; g.sBe = 6LL * 2048 * 512; g.sBi = 0; g.ldB = 512;
      g.C = f1; g.sCe = (long long)TOK * 2048; g.sCi = 0; g.ldC = 2048;
      g.M = TOK; g.N = 2048; g.K = 512; g.iPerE = 1;
      gemm_kernel<M_RELU, false, 128, 128><<<dim3(32, 16, 2), 256, 0, stream>>>(g);
    }
    {  // T1 = F1 @ W2 (fp32 out)
      GemmArgs g = {};
      g.A = f1; g.sAe = (long long)TOK * 2048; g.sAi = 0; g.ldA = 2048;
      g.B = w2T + (long long)j * 512 * 2048; g.sBe = 6LL * 512 * 2048; g.sBi = 0; g.ldB = 2048;
      g.Cf = t1f; g.sCe = (long long)TOK * 512; g.sCi = 0; g.ldC = 512;
      g.M = TOK; g.N = 512; g.K = 2048; g.iPerE = 1;
      gemm_kernel<M_F32, false, 64, 128><<<dim3(64, 4, 2), 256, 0, stream>>>(g);
    }
    // state = LN(H + ff); last layer writes final output directly (concat + reverse fused)
    ln_kernel<<<dim3(4096, 2), 64, 0, stream>>>(Sf, t1f, ln_a, ln_b, (j * 4 + 2) * 512, Sb, Sf,
                                                (j == 5) ? 1 : 0, out);
  }
}

// Round 2
// 1274.510 us; speedup vs baseline: 1.0280x; 1.0053x over previous
//
#include <hip/hip_runtime.h>

typedef __bf16 bf16;
typedef __bf16 bf16x8 __attribute__((ext_vector_type(8)));
typedef __bf16 bf16x4 __attribute__((ext_vector_type(4)));
typedef __bf16 bf16x2 __attribute__((ext_vector_type(2)));
typedef float f32x4 __attribute__((ext_vector_type(4)));

typedef __attribute__((address_space(3))) void lds_void_t;
typedef const __attribute__((address_space(1))) void gbl_void_t;

#define TOK 4096
#define KBROWS 5120

enum { M_BF16 = 0, M_F32 = 1, M_RELU = 2, M_QKV = 3, M_SCOREXP = 4, M_PV = 5 };

struct GemmArgs {
  const bf16* A; long long sAe, sAi; int ldA;
  const bf16* B; long long sBe, sBi; int ldB;
  const bf16* B2; long long sB2e; int ldB2;
  bf16* C; float* Cf; long long sCe, sCi; int ldC;
  int M, N, K, iPerE;
  bf16 *quv, *kbuf, *vt;
  const float *uvA, *uvB;
  float scale;
};

// ---------------- GEMM: C = A @ B^T, A (MxK) row-major, B (NxK) row-major ----------------
// Staging via global_load_lds; lane (8r+c) fetches chunk c^r -> XOR-swizzled LDS, frag reads
// sw=(4s+quad)^l7 are 0-bank-conflict. M_SCOREXP: epilogue exp (bounded logits, mask->0).
// M_PV: A-frags cover each P row's full K exactly once -> row-sum l computed in-loop, /l in epi.
template<int MODE, bool SPLITB, int TM, int TN>
__global__ __launch_bounds__(256, 4)
void gemm_kernel(GemmArgs g) {
  constexpr int FA = TM / 32, FB = TN / 32;
  int z = blockIdx.z;
  int e = z / g.iPerE;
  int i = z % g.iPerE;
  const bf16* A = g.A + e * g.sAe + i * g.sAi;
  const bf16* B = g.B + e * g.sBe + i * g.sBi;
  const bf16* B2 = nullptr;
  if constexpr (SPLITB) B2 = g.B2 + e * g.sB2e;

  int tm = blockIdx.x * TM;
  int tn = blockIdx.y * TN;

  __shared__ uint4 As4[TM * 8];
  __shared__ uint4 Bs4[TN * 8];
  __shared__ float ls[MODE == M_PV ? TM : 1];
  bf16* As_lds = (bf16*)As4;
  bf16* Bs_lds = (bf16*)Bs4;

  int tid = threadIdx.x;
  int wave = tid >> 6, lane = tid & 63;
  int wm = (wave >> 1) * (TM / 2), wn = (wave & 1) * (TN / 2);
  int quad = lane >> 4, l15 = lane & 15;
  int l7 = l15 & 7;
  int l8r = lane >> 3, l8c = lane & 7;
  int fc = l8c ^ l8r;

  f32x4 acc[FA][FB] = {};
  float lreg[FA];
#pragma unroll
  for (int t = 0; t < FA; ++t) lreg[t] = 0.f;

  for (int k0 = 0; k0 < g.K; k0 += 64) {
#pragma unroll
    for (int ii = 0; ii < FA; ++ii) {
      int rowbase = (wave * FA + ii) * 8;
      int r = rowbase + l8r;
      const bf16* gp = &A[(long long)(tm + r) * g.ldA + k0 + fc * 8];
      __builtin_amdgcn_global_load_lds((gbl_void_t*)gp, (lds_void_t*)&As_lds[rowbase * 64], 16, 0, 0);
    }
#pragma unroll
    for (int ii = 0; ii < FB; ++ii) {
      int rowbase = (wave * FB + ii) * 8;
      int r = rowbase + l8r;
      const bf16* gp;
      if constexpr (SPLITB) {
        int kk = k0 + fc * 8;
        gp = (kk < 512) ? &B[(long long)(tn + r) * g.ldB + kk]
                        : &B2[(long long)(tn + r) * g.ldB2 + (kk - 512)];
      } else {
        gp = &B[(long long)(tn + r) * g.ldB + k0 + fc * 8];
      }
      __builtin_amdgcn_global_load_lds((gbl_void_t*)gp, (lds_void_t*)&Bs_lds[rowbase * 64], 16, 0, 0);
    }
    __syncthreads();
#pragma unroll
    for (int s = 0; s < 2; ++s) {
      int sw = (s * 4 + quad) ^ l7;
      bf16x8 af[FA], bfr[FB];
#pragma unroll
      for (int t = 0; t < FA; ++t) af[t]  = ((const bf16x8*)As4)[(wm + t * 16 + l15) * 8 + sw];
#pragma unroll
      for (int t = 0; t < FB; ++t) bfr[t] = ((const bf16x8*)Bs4)[(wn + t * 16 + l15) * 8 + sw];
      if constexpr (MODE == M_PV) {
#pragma unroll
        for (int t = 0; t < FA; ++t)
#pragma unroll
          for (int q2 = 0; q2 < 8; ++q2) lreg[t] += (float)af[t][q2];
      }
#pragma unroll
      for (int a = 0; a < FA; ++a)
#pragma unroll
        for (int b = 0; b < FB; ++b)
          acc[a][b] = __builtin_amdgcn_mfma_f32_16x16x32_bf16(af[a], bfr[b], acc[a][b], 0, 0, 0);
    }
    __syncthreads();
  }

  if constexpr (MODE == M_PV) {
    // rowsum l: lane holds partial of row (wm + t*16 + l15); reduce across quads
#pragma unroll
    for (int t = 0; t < FA; ++t) {
      lreg[t] += __shfl_xor(lreg[t], 16);
      lreg[t] += __shfl_xor(lreg[t], 32);
      if (quad == 0) ls[wm + t * 16 + l15] = lreg[t];
    }
    __syncthreads();
  }

  // epilogues. C/D layout: col = lane&15, row = quad*4 + reg (m89-verified)
  if constexpr (MODE == M_QKV) {
    const float* uv = e ? g.uvB : g.uvA;
#pragma unroll
    for (int a = 0; a < FA; ++a) {
      int mB = tm + wm + a * 16 + quad * 4;
#pragma unroll
      for (int b = 0; b < FB; ++b) {
        int col = tn + wn + b * 16 + l15;
        int region = col >> 9, cin = col & 511;
        float u0 = 0.f, v0 = 0.f;
        if (region == 0) { u0 = uv[cin]; v0 = uv[512 + cin]; }
#pragma unroll
        for (int r = 0; r < 4; ++r) {
          int m = mB + r;
          float val = acc[a][b][r];
          if (region == 0) {
            long long qb = (long long)e * TOK * 1024 + (long long)m * 1024;
            g.quv[qb + cin]       = (bf16)(val + u0);
            g.quv[qb + 512 + cin] = (bf16)(val + v0);
          } else if (region == 1) {
            g.kbuf[(long long)e * KBROWS * 512 + (long long)(1024 + m) * 512 + cin] = (bf16)val;
          } else {  // region 2: S@Wvo -> vwoT[od][1024+token] (transposed scatter)
            g.vt[(long long)e * 512 * KBROWS + (long long)cin * KBROWS + 1024 + m] = (bf16)val;
          }
        }
      }
    }
  } else if constexpr (MODE == M_SCOREXP) {
    bf16* C = g.C + e * g.sCe + i * g.sCi;
    int T = 1024 - ((i < 2 ? i : 2) << 9);   // mask cols < T
#pragma unroll
    for (int a = 0; a < FA; ++a) {
      int mB = tm + wm + a * 16 + quad * 4;
#pragma unroll
      for (int b = 0; b < FB; ++b) {
        int col = tn + wn + b * 16 + l15;
        float bias = (col < T) ? -1e9f : 0.0f;
#pragma unroll
        for (int r = 0; r < 4; ++r)
          C[(long long)(mB + r) * g.ldC + col] = (bf16)__expf(acc[a][b][r] * g.scale + bias);
      }
    }
  } else if constexpr (MODE == M_PV) {
    float* Cf = g.Cf + e * g.sCe + i * g.sCi;
#pragma unroll
    for (int a = 0; a < FA; ++a) {
      int lrow = wm + a * 16 + quad * 4;
      int mB = tm + lrow;
#pragma unroll
      for (int b = 0; b < FB; ++b) {
        int col = tn + wn + b * 16 + l15;
#pragma unroll
        for (int r = 0; r < 4; ++r)
          Cf[(long long)(mB + r) * g.ldC + col] = acc[a][b][r] / ls[lrow + r];
      }
    }
  } else {
#pragma unroll
    for (int a = 0; a < FA; ++a) {
      int mB = tm + wm + a * 16 + quad * 4;
#pragma unroll
      for (int b = 0; b < FB; ++b) {
        int col = tn + wn + b * 16 + l15;
#pragma unroll
        for (int r = 0; r < 4; ++r) {
          float val = acc[a][b][r];
          if constexpr (MODE == M_RELU) val = val > 0.f ? val : 0.f;
          if constexpr (MODE == M_F32) {
            float* Cf = g.Cf + e * g.sCe + i * g.sCi;
            Cf[(long long)(mB + r) * g.ldC + col] = val;
          } else {
            bf16* C = g.C + e * g.sCe + i * g.sCi;
            C[(long long)(mB + r) * g.ldC + col] = (bf16)val;
          }
        }
      }
    }
  }
}

// ---------------- unified weight prep ----------------
// v2: each block processes TWO adjacent tiles (same matrix, same rows, adjacent 64-col
// ranges — class boundaries and per-mat tile counts are all even, so a pair never spans
// matrices). All 8 float4 loads are hoisted into registers before any LDS write, LDS is
// double-buffered, one barrier per 2 tiles: doubles in-flight load bytes, halves barriers.
__device__ inline void prep_locate(int id, const float* qa, const float* qb,
                                   const float* oa, const float* ob,
                                   const float* w1a, const float* w1b,
                                   const float* w2a, const float* w2b,
                                   bf16* wqkvT, bf16* wrT, bf16* wvPlain, bf16* woT,
                                   bf16* w1T, bf16* w2T,
                                   const float*& src, bf16*& dst, int& R, int& C,
                                   int& tx, int& ty, bool& plain) {
  plain = false;
  if (id < 3072) {          // Wqkvr: 48 mats x 64 tiles
    int mat = id >> 6, tile = id & 63;
    tx = tile & 7; ty = tile >> 3;
    int e = mat / 24, rj = mat % 24, j = rj >> 2, c = rj & 3;
    src = (e ? qb : qa) + (long long)(j * 4 + c) * 262144;
    R = 512; C = 512;
    if (c < 2)        dst = wqkvT + ((long long)(e * 6 + j) * 3 + c) * 262144;
    else if (c == 2) { dst = wvPlain + (long long)(e * 6 + j) * 262144; plain = true; }
    else              dst = wrT + (long long)(e * 6 + j) * 262144;
  } else if (id < 3840) {   // Wo: 12 mats x 64 tiles
    int id2 = id - 3072; int mat = id2 >> 6, tile = id2 & 63;
    tx = tile & 7; ty = tile >> 3;
    int e = mat / 6, j = mat % 6;
    src = (e ? ob : oa) + (long long)j * 262144;
    dst = woT + (long long)mat * 262144; R = 512; C = 512;
  } else if (id < 6912) {   // W1 (512x2048): 12 mats x 256 tiles
    int id2 = id - 3840; int mat = id2 >> 8, tile = id2 & 255;
    tx = tile & 31; ty = tile >> 5;
    int e = mat / 6, j = mat % 6;
    src = (e ? w1b : w1a) + (long long)j * 512 * 2048;
    dst = w1T + (long long)mat * 512 * 2048; R = 512; C = 2048;
  } else {                  // W2 (2048x512): 12 mats x 256 tiles
    int id2 = id - 6912; int mat = id2 >> 8, tile = id2 & 255;
    tx = tile & 7; ty = tile >> 3;
    int e = mat / 6, j = mat % 6;
    src = (e ? w2b : w2a) + (long long)j * 2048 * 512;
    dst = w2T + (long long)mat * 2048 * 512; R = 2048; C = 512;
  }
}

__global__ __launch_bounds__(256)
void prep_weights(const float* qa, const float* qb, const float* oa, const float* ob,
                  const float* w1a, const float* w1b, const float* w2a, const float* w2b,
                  bf16* wqkvT, bf16* wrT, bf16* wvPlain, bf16* woT, bf16* w1T, bf16* w2T) {
  int id0 = blockIdx.x * 2;
  const float* src; bf16* dst; int R, C, tx0, ty; bool plain;
  prep_locate(id0, qa, qb, oa, ob, w1a, w1b, w2a, w2b,
              wqkvT, wrT, wvPlain, woT, w1T, w2T, src, dst, R, C, tx0, ty, plain);
  int r0 = ty * 64;
  int tid = threadIdx.x;

  if (plain) {
    // pure cast: all 8 float4 reads in flight, then 2x 16B bf16x8 stores per tile
    int c8 = (tid & 7) * 8;
    int r8 = tid >> 3;                       // 0..31
    float4 f[2][4];
#pragma unroll
    for (int p = 0; p < 2; ++p) {
      int c0 = (tx0 + p) * 64;
#pragma unroll
      for (int rep = 0; rep < 2; ++rep) {
        const float* sp = &src[(long long)(r0 + r8 + rep * 32) * C + c0 + c8];
        f[p][rep * 2]     = *(const float4*)sp;
        f[p][rep * 2 + 1] = *(const float4*)(sp + 4);
      }
    }
#pragma unroll
    for (int p = 0; p < 2; ++p) {
      int c0 = (tx0 + p) * 64;
#pragma unroll
      for (int rep = 0; rep < 2; ++rep) {
        float4 f0 = f[p][rep * 2], f1 = f[p][rep * 2 + 1];
        bf16 o[8] __attribute__((aligned(16))) =
          {(bf16)f0.x, (bf16)f0.y, (bf16)f0.z, (bf16)f0.w,
           (bf16)f1.x, (bf16)f1.y, (bf16)f1.z, (bf16)f1.w};
        *(bf16x8*)&dst[(long long)(r0 + r8 + rep * 32) * C + c0 + c8] = *(const bf16x8*)o;
      }
    }
  } else {
    // transpose via swizzled LDS: t_logical[srcCol][srcRow], pitch 68,
    // physical col = logicalCol ^ (((row>>4)&3)<<2); double-buffered for the tile pair
    __shared__ bf16 t[2][64 * 68];
    int l15 = tid & 15;                      // src-col group
    int hi  = tid >> 4;                      // 0..15 src-row
    int cc = l15 * 4;
    float4 f[2][4];
#pragma unroll
    for (int p = 0; p < 2; ++p) {
      int c0 = (tx0 + p) * 64;
#pragma unroll
      for (int rep = 0; rep < 4; ++rep)
        f[p][rep] = *(const float4*)&src[(long long)(r0 + hi + rep * 16) * C + c0 + cc];
    }
#pragma unroll
    for (int p = 0; p < 2; ++p)
#pragma unroll
      for (int rep = 0; rep < 4; ++rep) {
        int rr = hi + rep * 16;
        float v[4] = {f[p][rep].x, f[p][rep].y, f[p][rep].z, f[p][rep].w};
#pragma unroll
        for (int i2 = 0; i2 < 4; ++i2) {
          int row = cc + i2;
          int col = rr ^ (((row >> 4) & 3) << 2);
          t[p][row * 68 + col] = (bf16)v[i2];
        }
      }
    __syncthreads();
    int oc = tid >> 2;                       // output row (src col) 0..63
    int kk = tid & 3;                        // 16-elem chunk
#pragma unroll
    for (int p = 0; p < 2; ++p) {
      int c0 = (tx0 + p) * 64;
      bf16 outv[16] __attribute__((aligned(16)));
#pragma unroll
      for (int u = 0; u < 4; ++u) {
        int col = (16 * kk + 4 * u) ^ (((oc >> 4) & 3) << 2);
        *(bf16x4*)&outv[u * 4] = *(const bf16x4*)&t[p][oc * 68 + col];
      }
      bf16* dp = &dst[(long long)(c0 + oc) * R + r0 + 16 * kk];
      *(bf16x8*)dp       = *(const bf16x8*)&outv[0];
      *(bf16x8*)(dp + 8) = *(const bf16x8*)&outv[8];
    }
  }
}

// ---------------- misc setup kernels ----------------
__global__ __launch_bounds__(256)
void sinusoid_kernel(bf16* rb) {
  int i = blockIdx.x, m = threadIdx.x;
  float p = (float)(1535 - i);
  float inv = expf(-((float)(2 * m) * (1.0f / 512.0f)) * 9.210340371976184f);
  float ang = p * inv;
  bf16x2 v = {(bf16)sinf(ang), (bf16)cosf(ang)};
  *(bf16x2*)&rb[(long long)i * 512 + 2 * m] = v;
}

__global__ __launch_bounds__(128)
void embed_kernel(const int* src, const float* emb, bf16* Sb, float* Sf) {
  int row = blockIdx.x, e = blockIdx.y, tid = threadIdx.x;
  int tok = e ? src[4095 - row] : src[row];
  long long base = ((long long)e * TOK + row) * 512 + tid * 4;
  float4 f = *(const float4*)&emb[(long long)tok * 512 + tid * 4];
  *(float4*)&Sf[base] = f;
  bf16 o[4] __attribute__((aligned(8))) = {(bf16)f.x, (bf16)f.y, (bf16)f.z, (bf16)f.w};
  *(bf16x4*)&Sb[base] = *(const bf16x4*)o;
}

// zero the "no-memory" regions: kbuf rows 0..1023, vwoT cols 0..1023
__global__ __launch_bounds__(256)
void zero_kv(bf16* kbuf, bf16* vwoT) {
  int r = blockIdx.x, e = blockIdx.y, which = blockIdx.z, tid = threadIdx.x;
  uint4 z = {0u, 0u, 0u, 0u};
  if (which == 0) {
    if (tid < 64) ((uint4*)(kbuf + ((long long)e * KBROWS + r) * 512))[tid] = z;
  } else if (r < 512) {
    if (tid < 128) ((uint4*)(vwoT + ((long long)e * 512 + r) * KBROWS))[tid] = z;
  }
}

// ---------------- residual + layernorm; outMode 1 = write final output directly ----------------
// v2: lane owns 8 CONTIGUOUS elements -> float4 loads/stores + bf16x8 store (was all scalar)
__global__ __launch_bounds__(64)
void ln_kernel(const float* Xf, const float* Tf, const float* lnA, const float* lnB,
               int gOff, bf16* OutB, float* OutF, int outMode, float* finalOut) {
  int row = blockIdx.x, e = blockIdx.y;
  long long base = ((long long)e * TOK + row) * 512;
  const float* ln = e ? lnB : lnA;
  int lane = threadIdx.x;
  int d0 = lane * 8;
  float4 x0 = *(const float4*)&Xf[base + d0];
  float4 x1 = *(const float4*)&Xf[base + d0 + 4];
  float4 t0 = *(const float4*)&Tf[base + d0];
  float4 t1 = *(const float4*)&Tf[base + d0 + 4];
  float vals[8] = {x0.x + t0.x, x0.y + t0.y, x0.z + t0.z, x0.w + t0.w,
                   x1.x + t1.x, x1.y + t1.y, x1.z + t1.z, x1.w + t1.w};
  float s = 0.f;
#pragma unroll
  for (int k = 0; k < 8; ++k) s += vals[k];
  for (int off = 32; off; off >>= 1) s += __shfl_xor(s, off);
  float mu = s * (1.0f / 512.0f);
  float vs = 0.f;
#pragma unroll
  for (int k = 0; k < 8; ++k) { float d = vals[k] - mu; vs += d * d; }
  for (int off = 32; off; off >>= 1) vs += __shfl_xor(vs, off);
  float rstd = rsqrtf(vs * (1.0f / 512.0f) + 1e-5f);
  float4 g0 = *(const float4*)&ln[gOff + d0];
  float4 g1 = *(const float4*)&ln[gOff + d0 + 4];
  float4 b0 = *(const float4*)&ln[gOff + 512 + d0];
  float4 b1 = *(const float4*)&ln[gOff + 512 + d0 + 4];
  float gm[8] = {g0.x, g0.y, g0.z, g0.w, g1.x, g1.y, g1.z, g1.w};
  float bt[8] = {b0.x, b0.y, b0.z, b0.w, b1.x, b1.y, b1.z, b1.w};
  float y[8];
#pragma unroll
  for (int k = 0; k < 8; ++k) y[k] = (vals[k] - mu) * rstd * gm[k] + bt[k];
  if (outMode == 0) {
    bf16 ob8[8] __attribute__((aligned(16)));
#pragma unroll
    for (int k = 0; k < 8; ++k) ob8[k] = (bf16)y[k];
    *(bf16x8*)&OutB[base + d0] = *(const bf16x8*)ob8;
    float4 ya = {y[0], y[1], y[2], y[3]}, yb = {y[4], y[5], y[6], y[7]};
    *(float4*)&OutF[base + d0]     = ya;
    *(float4*)&OutF[base + d0 + 4] = yb;
  } else {
    long long ob = e ? ((long long)(4095 - row) * 1024 + 512) : ((long long)row * 1024);
    float4 ya = {y[0], y[1], y[2], y[3]}, yb = {y[4], y[5], y[6], y[7]};
    *(float4*)&finalOut[ob + d0]     = ya;
    *(float4*)&finalOut[ob + d0 + 4] = yb;
  }
}

extern "C" void kernel_launch(void* const* d_in, const int* in_sizes, int n_in,
                              void* d_out, int out_size, void* d_ws, size_t ws_size,
                              hipStream_t stream) {
  const int*   src   = (const int*)d_in[0];
  const float* emb   = (const float*)d_in[2];
  const float* Wq_a  = (const float*)d_in[3];
  const float* Wo_a  = (const float*)d_in[4];
  const float* W1_a  = (const float*)d_in[5];
  const float* W2_a  = (const float*)d_in[6];
  const float* ln_a  = (const float*)d_in[7];
  const float* uv_a  = (const float*)d_in[8];
  const float* Wq_b  = (const float*)d_in[9];
  const float* Wo_b  = (const float*)d_in[10];
  const float* W1_b  = (const float*)d_in[11];
  const float* W2_b  = (const float*)d_in[12];
  const float* ln_b  = (const float*)d_in[13];
  const float* uv_b  = (const float*)d_in[14];
  float* out = (float*)d_out;

  char* w = (char*)d_ws;
  size_t off = 0;
  auto alloc = [&](long long elems, int esz) -> char* {
    char* p = w + off;
    off += (size_t)elems * esz;
    off = (off + 255) & ~(size_t)255;
    return p;
  };
  bf16* wqkvT = (bf16*)alloc(2LL * 6 * 1536 * 512, 2);  // rows: q, k, (wvo = Wv@Wo set at runtime)
  bf16* woT   = (bf16*)alloc(2LL * 6 * 512 * 512, 2);
  bf16* w1T   = (bf16*)alloc(2LL * 6 * 2048 * 512, 2);
  bf16* w2T   = (bf16*)alloc(2LL * 6 * 512 * 2048, 2);
  bf16* pk    = (bf16*)alloc(2LL * 6 * 1536 * 512, 2);
  bf16* Sb    = (bf16*)alloc(2LL * TOK * 512, 2);
  float* Sf   = (float*)alloc(2LL * TOK * 512, 4);
  bf16* quv   = (bf16*)alloc(2LL * TOK * 1024, 2);
  bf16* kbuf  = (bf16*)alloc(2LL * KBROWS * 512, 2);
  bf16* vwoT  = (bf16*)alloc(2LL * 512 * KBROWS, 2);
  bf16* P     = (bf16*)alloc(2LL * 8 * 512 * 1536, 2);
  float* t1f  = (float*)alloc(2LL * TOK * 512, 4);
  bf16* f1    = (bf16*)alloc(2LL * TOK * 2048, 2);
  // overlays (setup-only, inside f1's region; f1 first written in layer loop):
  bf16* rb      = f1;                          // 1.5 MB
  bf16* wrT     = f1 + 1024LL * 1024;          // 6 MB at +2MB
  bf16* wvPlain = f1 + 4096LL * 1024;          // 6 MB at +8MB

  if (off > ws_size) return;

  // ---- setup ----
  prep_weights<<<4992, 256, 0, stream>>>(Wq_a, Wq_b, Wo_a, Wo_b, W1_a, W1_b, W2_a, W2_b,
                                         wqkvT, wrT, wvPlain, woT, w1T, w2T);
  sinusoid_kernel<<<1536, 256, 0, stream>>>(rb);
  embed_kernel<<<dim3(4096, 2), 128, 0, stream>>>(src, emb, Sb, Sf);
  zero_kv<<<dim3(1024, 2, 2), 256, 0, stream>>>(kbuf, vwoT);

  {  // pk[e][j] = R @ Wr[e][j]
    GemmArgs g = {};
    g.A = rb; g.sAe = 0; g.sAi = 0; g.ldA = 512;
    g.B = wrT; g.sBe = 0; g.sBi = 512LL * 512; g.ldB = 512;
    g.C = pk; g.sCe = 0; g.sCi = 1536LL * 512; g.ldC = 512;
    g.M = 1536; g.N = 512; g.K = 512; g.iPerE = 12;
    gemm_kernel<M_BF16, false, 128, 128><<<dim3(12, 4, 12), 256, 0, stream>>>(g);
  }
  {  // wvoT[e][j][od][k] = Wvo[k][od] = sum_v Wv[k][v] Wo[v][od]  -> wqkvT slot 2
    GemmArgs g = {};
    g.A = woT; g.sAe = 6LL * 262144; g.sAi = 262144; g.ldA = 512;       // A[od][v] = Wo[v][od]
    g.B = wvPlain; g.sBe = 6LL * 262144; g.sBi = 262144; g.ldB = 512;   // B[k][v]  = Wv[k][v]
    g.C = wqkvT + 2LL * 262144; g.sCe = 18LL * 262144; g.sCi = 3LL * 262144; g.ldC = 512;
    g.M = 512; g.N = 512; g.K = 512; g.iPerE = 6;
    gemm_kernel<M_BF16, false, 128, 128><<<dim3(4, 4, 12), 256, 0, stream>>>(g);
  }

  const float scale = 0.044194173824159216f;  // 1/sqrt(512)

  for (int j = 0; j < 6; ++j) {
    {  // QKV: q+u/q+v -> quv, k -> kbuf(+1024), S@Wvo -> vwoT(+1024, transposed)
      GemmArgs g = {};
      g.A = Sb; g.sAe = (long long)TOK * 512; g.sAi = 0; g.ldA = 512;
      g.B = wqkvT + (long long)j * 1536 * 512; g.sBe = 6LL * 1536 * 512; g.sBi = 0; g.ldB = 512;
      g.M = TOK; g.N = 1536; g.K = 512; g.iPerE = 1;
      g.quv = quv; g.kbuf = kbuf; g.vt = vwoT; g.uvA = uv_a; g.uvB = uv_b;
      gemm_kernel<M_QKV, false, 128, 128><<<dim3(32, 12, 2), 256, 0, stream>>>(g);
    }
    {  // P = exp(qu@Kwin^T + qv@pk^T scaled+masked)  (no-max softmax numerator)
      GemmArgs g = {};
      g.A = quv; g.sAe = (long long)TOK * 1024; g.sAi = 512LL * 1024; g.ldA = 1024;
      g.B = kbuf; g.sBe = (long long)KBROWS * 512; g.sBi = 512LL * 512; g.ldB = 512;
      g.B2 = pk + (long long)j * 1536 * 512; g.sB2e = 6LL * 1536 * 512; g.ldB2 = 512;
      g.C = P; g.sCe = 8LL * 512 * 1536; g.sCi = 512LL * 1536; g.ldC = 1536;
      g.M = 512; g.N = 1536; g.K = 1024; g.iPerE = 8;
      g.scale = scale;
      gemm_kernel<M_SCOREXP, true, 128, 128><<<dim3(4, 12, 16), 256, 0, stream>>>(g);
    }
    {  // attn_proj = (P @ VWowin) / rowsum(P)  -> fp32 t1f
      GemmArgs g = {};
      g.A = P; g.sAe = 8LL * 512 * 1536; g.sAi = 512LL * 1536; g.ldA = 1536;
      g.B = vwoT; g.sBe = 512LL * KBROWS; g.sBi = 512; g.ldB = KBROWS;
      g.Cf = t1f; g.sCe = (long long)TOK * 512; g.sCi = 512LL * 512; g.ldC = 512;
      g.M = 512; g.N = 512; g.K = 1536; g.iPerE = 8;
      gemm_kernel<M_PV, false, 64, 128><<<dim3(8, 4, 16), 256, 0, stream>>>(g);
    }
    // H = LN(state + attn_out) — in-place into Sb/Sf
    ln_kernel<<<dim3(4096, 2), 64, 0, stream>>>(Sf, t1f, ln_a, ln_b, (j * 4 + 0) * 512, Sb, Sf, 0, out);
    {  // F1 = relu(H @ W1)
      GemmArgs g = {};
      g.A = Sb; g.sAe = (long long)TOK * 512; g.sAi = 0; g.ldA = 512;
      g.B = w1T + (long long)j * 2048 * 512; g.sBe = 6LL * 2048 * 512; g.sBi = 0; g.ldB = 512;
      g.C = f1; g.sCe = (long long)TOK * 2048; g.sCi = 0; g.ldC = 2048;
      g.M = TOK; g.N = 2048; g.K = 512; g.iPerE = 1;
      gemm_kernel<M_RELU, false, 128, 128><<<dim3(32, 16, 2), 256, 0, stream>>>(g);
    }
    {  // T1 = F1 @ W2 (fp32 out)
      GemmArgs g = {};
      g.A = f1; g.sAe = (long long)TOK * 2048; g.sAi = 0; g.ldA = 2048;
      g.B = w2T + (long long)j * 512 * 2048; g.sBe = 6LL * 512 * 2048; g.sBi = 0; g.ldB = 2048;
      g.Cf = t1f; g.sCe = (long long)TOK * 512; g.sCi = 0; g.ldC = 512;
      g.M = TOK; g.N = 512; g.K = 2048; g.iPerE = 1;
      gemm_kernel<M_F32, false, 64, 128><<<dim3(64, 4, 2), 256, 0, stream>>>(g);
    }
    // state = LN(H + ff); last layer writes final output directly (concat + reverse fused)
    ln_kernel<<<dim3(4096, 2), 64, 0, stream>>>(Sf, t1f, ln_a, ln_b, (j * 4 + 2) * 512, Sb, Sf,
                                                (j == 5) ? 1 : 0, out);
  }
}

// Round 3
// 1242.824 us; speedup vs baseline: 1.0542x; 1.0255x over previous
//
#include <hip/hip_runtime.h>

typedef __bf16 bf16;
typedef __bf16 bf16x8 __attribute__((ext_vector_type(8)));
typedef __bf16 bf16x4 __attribute__((ext_vector_type(4)));
typedef __bf16 bf16x2 __attribute__((ext_vector_type(2)));
typedef float f32x4 __attribute__((ext_vector_type(4)));

typedef __attribute__((address_space(3))) void lds_void_t;
typedef const __attribute__((address_space(1))) void gbl_void_t;

#define TOK 4096
#define KBROWS 5120

enum { M_BF16 = 0, M_F32 = 1, M_RELU = 2, M_QKV = 3, M_SCOREXP = 4, M_PV = 5 };

struct GemmArgs {
  const bf16* A; long long sAe, sAi; int ldA;
  const bf16* B; long long sBe, sBi; int ldB;
  const bf16* B2; long long sB2e; int ldB2;
  bf16* C; float* Cf; long long sCe, sCi; int ldC;
  int M, N, K, iPerE;
  bf16 *quv, *kbuf, *vt;
  const float *uvA, *uvB;
  float scale;
};

// ---------------- GEMM: C = A @ B^T, A (MxK) row-major, B (NxK) row-major ----------------
// Staging via global_load_lds; lane (8r+c) fetches chunk c^r -> XOR-swizzled LDS, frag reads
// sw=(4s+quad)^l7 are 0-bank-conflict. M_SCOREXP: epilogue exp (bounded logits, mask->0).
// M_PV: A-frags cover each P row's full K exactly once -> row-sum l computed in-loop, /l in epi.
// M_QKV region 2 (vt transposed scatter): routed through LDS (reusing the staging buffer,
// 128x128 bf16 = 32 KB) with involution swizzle m ^= (cin&15)<<3 -> bf16x8 stores, full-line
// output rows (was: scalar 2B stores at 10KB stride = 4x write amplification).
template<int MODE, bool SPLITB, int TM, int TN>
__global__ __launch_bounds__(256, 4)
void gemm_kernel(GemmArgs g) {
  constexpr int FA = TM / 32, FB = TN / 32;
  int z = blockIdx.z;
  int e = z / g.iPerE;
  int i = z % g.iPerE;
  const bf16* A = g.A + e * g.sAe + i * g.sAi;
  const bf16* B = g.B + e * g.sBe + i * g.sBi;
  const bf16* B2 = nullptr;
  if constexpr (SPLITB) B2 = g.B2 + e * g.sB2e;

  int tm = blockIdx.x * TM;
  int tn = blockIdx.y * TN;

  __shared__ uint4 smem[TM * 8 + TN * 8];
  uint4* As4 = smem;
  uint4* Bs4 = smem + TM * 8;
  __shared__ float ls[MODE == M_PV ? TM : 1];
  bf16* As_lds = (bf16*)As4;
  bf16* Bs_lds = (bf16*)Bs4;

  int tid = threadIdx.x;
  int wave = tid >> 6, lane = tid & 63;
  int wm = (wave >> 1) * (TM / 2), wn = (wave & 1) * (TN / 2);
  int quad = lane >> 4, l15 = lane & 15;
  int l7 = l15 & 7;
  int l8r = lane >> 3, l8c = lane & 7;
  int fc = l8c ^ l8r;

  f32x4 acc[FA][FB] = {};
  float lreg[FA];
#pragma unroll
  for (int t = 0; t < FA; ++t) lreg[t] = 0.f;

  for (int k0 = 0; k0 < g.K; k0 += 64) {
#pragma unroll
    for (int ii = 0; ii < FA; ++ii) {
      int rowbase = (wave * FA + ii) * 8;
      int r = rowbase + l8r;
      const bf16* gp = &A[(long long)(tm + r) * g.ldA + k0 + fc * 8];
      __builtin_amdgcn_global_load_lds((gbl_void_t*)gp, (lds_void_t*)&As_lds[rowbase * 64], 16, 0, 0);
    }
#pragma unroll
    for (int ii = 0; ii < FB; ++ii) {
      int rowbase = (wave * FB + ii) * 8;
      int r = rowbase + l8r;
      const bf16* gp;
      if constexpr (SPLITB) {
        int kk = k0 + fc * 8;
        gp = (kk < 512) ? &B[(long long)(tn + r) * g.ldB + kk]
                        : &B2[(long long)(tn + r) * g.ldB2 + (kk - 512)];
      } else {
        gp = &B[(long long)(tn + r) * g.ldB + k0 + fc * 8];
      }
      __builtin_amdgcn_global_load_lds((gbl_void_t*)gp, (lds_void_t*)&Bs_lds[rowbase * 64], 16, 0, 0);
    }
    __syncthreads();
#pragma unroll
    for (int s = 0; s < 2; ++s) {
      int sw = (s * 4 + quad) ^ l7;
      bf16x8 af[FA], bfr[FB];
#pragma unroll
      for (int t = 0; t < FA; ++t) af[t]  = ((const bf16x8*)As4)[(wm + t * 16 + l15) * 8 + sw];
#pragma unroll
      for (int t = 0; t < FB; ++t) bfr[t] = ((const bf16x8*)Bs4)[(wn + t * 16 + l15) * 8 + sw];
      if constexpr (MODE == M_PV) {
#pragma unroll
        for (int t = 0; t < FA; ++t)
#pragma unroll
          for (int q2 = 0; q2 < 8; ++q2) lreg[t] += (float)af[t][q2];
      }
#pragma unroll
      for (int a = 0; a < FA; ++a)
#pragma unroll
        for (int b = 0; b < FB; ++b)
          acc[a][b] = __builtin_amdgcn_mfma_f32_16x16x32_bf16(af[a], bfr[b], acc[a][b], 0, 0, 0);
    }
    __syncthreads();
  }

  if constexpr (MODE == M_PV) {
    // rowsum l: lane holds partial of row (wm + t*16 + l15); reduce across quads
#pragma unroll
    for (int t = 0; t < FA; ++t) {
      lreg[t] += __shfl_xor(lreg[t], 16);
      lreg[t] += __shfl_xor(lreg[t], 32);
      if (quad == 0) ls[wm + t * 16 + l15] = lreg[t];
    }
    __syncthreads();
  }

  // epilogues. C/D layout: col = lane&15, row = quad*4 + reg (m89-verified)
  if constexpr (MODE == M_QKV) {
    const float* uv = e ? g.uvB : g.uvA;
    int region = tn >> 9;   // block-uniform: TN=128 tiles never span a 512-col region
    if (region == 2) {
      // S@Wvo -> vwoT[od][1024+token]: transpose through LDS (smem free after K-loop barrier)
      bf16* sm = (bf16*)smem;   // 128x128 bf16 (requires TM==TN==128)
#pragma unroll
      for (int a = 0; a < FA; ++a) {
        int m_l = wm + a * 16 + quad * 4;
#pragma unroll
        for (int b = 0; b < FB; ++b) {
          int c_l = wn + b * 16 + l15;
          int mp = m_l ^ ((c_l & 15) << 3);
          bf16 v4[4] __attribute__((aligned(8)));
#pragma unroll
          for (int r = 0; r < 4; ++r) v4[r] = (bf16)acc[a][b][r];
          *(bf16x4*)&sm[c_l * 128 + mp] = *(const bf16x4*)v4;
        }
      }
      __syncthreads();
      int c_l = tid >> 1;
      int half = (tid & 1) * 64;
      long long vb = (long long)e * 512 * KBROWS + (long long)(tn - 1024 + c_l) * KBROWS + 1024 + tm;
#pragma unroll
      for (int u = 0; u < 8; ++u) {
        int m0 = half + u * 8;
        int mp = m0 ^ ((c_l & 15) << 3);
        *(bf16x8*)&g.vt[vb + m0] = *(const bf16x8*)&sm[c_l * 128 + mp];
      }
    } else if (region == 0) {
#pragma unroll
      for (int a = 0; a < FA; ++a) {
        int mB = tm + wm + a * 16 + quad * 4;
#pragma unroll
        for (int b = 0; b < FB; ++b) {
          int cin = tn + wn + b * 16 + l15;
          float u0 = uv[cin], v0 = uv[512 + cin];
#pragma unroll
          for (int r = 0; r < 4; ++r) {
            int m = mB + r;
            float val = acc[a][b][r];
            long long qb = (long long)e * TOK * 1024 + (long long)m * 1024;
            g.quv[qb + cin]       = (bf16)(val + u0);
            g.quv[qb + 512 + cin] = (bf16)(val + v0);
          }
        }
      }
    } else {
#pragma unroll
      for (int a = 0; a < FA; ++a) {
        int mB = tm + wm + a * 16 + quad * 4;
#pragma unroll
        for (int b = 0; b < FB; ++b) {
          int cin = (tn - 512) + wn + b * 16 + l15;
#pragma unroll
          for (int r = 0; r < 4; ++r)
            g.kbuf[(long long)e * KBROWS * 512 + (long long)(1024 + mB + r) * 512 + cin] =
                (bf16)acc[a][b][r];
        }
      }
    }
  } else if constexpr (MODE == M_SCOREXP) {
    bf16* C = g.C + e * g.sCe + i * g.sCi;
    int T = 1024 - ((i < 2 ? i : 2) << 9);   // mask cols < T
#pragma unroll
    for (int a = 0; a < FA; ++a) {
      int mB = tm + wm + a * 16 + quad * 4;
#pragma unroll
      for (int b = 0; b < FB; ++b) {
        int col = tn + wn + b * 16 + l15;
        float bias = (col < T) ? -1e9f : 0.0f;
#pragma unroll
        for (int r = 0; r < 4; ++r)
          C[(long long)(mB + r) * g.ldC + col] = (bf16)__expf(acc[a][b][r] * g.scale + bias);
      }
    }
  } else if constexpr (MODE == M_PV) {
    float* Cf = g.Cf + e * g.sCe + i * g.sCi;
#pragma unroll
    for (int a = 0; a < FA; ++a) {
      int lrow = wm + a * 16 + quad * 4;
      int mB = tm + lrow;
#pragma unroll
      for (int b = 0; b < FB; ++b) {
        int col = tn + wn + b * 16 + l15;
#pragma unroll
        for (int r = 0; r < 4; ++r)
          Cf[(long long)(mB + r) * g.ldC + col] = acc[a][b][r] / ls[lrow + r];
      }
    }
  } else {
#pragma unroll
    for (int a = 0; a < FA; ++a) {
      int mB = tm + wm + a * 16 + quad * 4;
#pragma unroll
      for (int b = 0; b < FB; ++b) {
        int col = tn + wn + b * 16 + l15;
#pragma unroll
        for (int r = 0; r < 4; ++r) {
          float val = acc[a][b][r];
          if constexpr (MODE == M_RELU) val = val > 0.f ? val : 0.f;
          if constexpr (MODE == M_F32) {
            float* Cf = g.Cf + e * g.sCe + i * g.sCi;
            Cf[(long long)(mB + r) * g.ldC + col] = val;
          } else {
            bf16* C = g.C + e * g.sCe + i * g.sCi;
            C[(long long)(mB + r) * g.ldC + col] = (bf16)val;
          }
        }
      }
    }
  }
}

// ---------------- unified setup: weight prep + sinusoid + embed + zero_kv, ONE dispatch ----------------
__device__ inline void prep_locate(int id, const float* qa, const float* qb,
                                   const float* oa, const float* ob,
                                   const float* w1a, const float* w1b,
                                   const float* w2a, const float* w2b,
                                   bf16* wqkvT, bf16* wrT, bf16* wvPlain, bf16* woT,
                                   bf16* w1T, bf16* w2T,
                                   const float*& src, bf16*& dst, int& R, int& C,
                                   int& tx, int& ty, bool& plain) {
  plain = false;
  if (id < 3072) {          // Wqkvr: 48 mats x 64 tiles
    int mat = id >> 6, tile = id & 63;
    tx = tile & 7; ty = tile >> 3;
    int e = mat / 24, rj = mat % 24, j = rj >> 2, c = rj & 3;
    src = (e ? qb : qa) + (long long)(j * 4 + c) * 262144;
    R = 512; C = 512;
    if (c < 2)        dst = wqkvT + ((long long)(e * 6 + j) * 3 + c) * 262144;
    else if (c == 2) { dst = wvPlain + (long long)(e * 6 + j) * 262144; plain = true; }
    else              dst = wrT + (long long)(e * 6 + j) * 262144;
  } else if (id < 3840) {   // Wo: 12 mats x 64 tiles
    int id2 = id - 3072; int mat = id2 >> 6, tile = id2 & 63;
    tx = tile & 7; ty = tile >> 3;
    int e = mat / 6, j = mat % 6;
    src = (e ? ob : oa) + (long long)j * 262144;
    dst = woT + (long long)mat * 262144; R = 512; C = 512;
  } else if (id < 6912) {   // W1 (512x2048): 12 mats x 256 tiles
    int id2 = id - 3840; int mat = id2 >> 8, tile = id2 & 255;
    tx = tile & 31; ty = tile >> 5;
    int e = mat / 6, j = mat % 6;
    src = (e ? w1b : w1a) + (long long)j * 512 * 2048;
    dst = w1T + (long long)mat * 512 * 2048; R = 512; C = 2048;
  } else {                  // W2 (2048x512): 12 mats x 256 tiles
    int id2 = id - 6912; int mat = id2 >> 8, tile = id2 & 255;
    tx = tile & 7; ty = tile >> 3;
    int e = mat / 6, j = mat % 6;
    src = (e ? w2b : w2a) + (long long)j * 2048 * 512;
    dst = w2T + (long long)mat * 2048 * 512; R = 2048; C = 512;
  }
}

// block-id ranges: [0,2496) prep (4 tiles each) | [2496,4032) sinusoid |
//                  [4032,8128) embed (2 rows)   | [8128,12224) zero_kv
__global__ __launch_bounds__(256)
void setup_kernel(const float* qa, const float* qb, const float* oa, const float* ob,
                  const float* w1a, const float* w1b, const float* w2a, const float* w2b,
                  bf16* wqkvT, bf16* wrT, bf16* wvPlain, bf16* woT, bf16* w1T, bf16* w2T,
                  bf16* rb, const int* src, const float* emb, bf16* Sb, float* Sf,
                  bf16* kbuf, bf16* vwoT) {
  __shared__ bf16 t[2][64 * 68];
  int bid = blockIdx.x;
  int tid = threadIdx.x;

  if (bid < 2496) {
    // ---- weight prep: 4 adjacent col-tiles (same mat/rows; boundaries all %4==0) ----
    int id0 = bid * 4;
    const float* src_w; bf16* dst; int R, C, tx0, ty; bool plain;
    prep_locate(id0, qa, qb, oa, ob, w1a, w1b, w2a, w2b,
                wqkvT, wrT, wvPlain, woT, w1T, w2T, src_w, dst, R, C, tx0, ty, plain);
    int r0 = ty * 64;

    if (plain) {
      int c8 = (tid & 7) * 8;
      int r8 = tid >> 3;                       // 0..31
      float4 f[4][4];
#pragma unroll
      for (int p = 0; p < 4; ++p) {
        int c0 = (tx0 + p) * 64;
#pragma unroll
        for (int rep = 0; rep < 2; ++rep) {
          const float* sp = &src_w[(long long)(r0 + r8 + rep * 32) * C + c0 + c8];
          f[p][rep * 2]     = *(const float4*)sp;
          f[p][rep * 2 + 1] = *(const float4*)(sp + 4);
        }
      }
#pragma unroll
      for (int p = 0; p < 4; ++p) {
        int c0 = (tx0 + p) * 64;
#pragma unroll
        for (int rep = 0; rep < 2; ++rep) {
          float4 f0 = f[p][rep * 2], f1 = f[p][rep * 2 + 1];
          bf16 o[8] __attribute__((aligned(16))) =
            {(bf16)f0.x, (bf16)f0.y, (bf16)f0.z, (bf16)f0.w,
             (bf16)f1.x, (bf16)f1.y, (bf16)f1.z, (bf16)f1.w};
          *(bf16x8*)&dst[(long long)(r0 + r8 + rep * 32) * C + c0 + c8] = *(const bf16x8*)o;
        }
      }
    } else {
      // two pairs through the same 2-buffer LDS; pair-B loads issued during pair-A store phase
      int l15 = tid & 15;                      // src-col group
      int hi  = tid >> 4;                      // 0..15 src-row
      int cc = l15 * 4;
      int oc = tid >> 2;                       // output row (src col) 0..63
      int kk = tid & 3;                        // 16-elem chunk
      float4 fA[2][4], fB[2][4];
#pragma unroll
      for (int p = 0; p < 2; ++p) {
        int c0 = (tx0 + p) * 64;
#pragma unroll
        for (int rep = 0; rep < 4; ++rep)
          fA[p][rep] = *(const float4*)&src_w[(long long)(r0 + hi + rep * 16) * C + c0 + cc];
      }
#pragma unroll
      for (int p = 0; p < 2; ++p)
#pragma unroll
        for (int rep = 0; rep < 4; ++rep) {
          int rr = hi + rep * 16;
          float v[4] = {fA[p][rep].x, fA[p][rep].y, fA[p][rep].z, fA[p][rep].w};
#pragma unroll
          for (int i2 = 0; i2 < 4; ++i2) {
            int row = cc + i2;
            int col = rr ^ (((row >> 4) & 3) << 2);
            t[p][row * 68 + col] = (bf16)v[i2];
          }
        }
      // issue pair-B loads before the barrier: latency hides under pair-A's store phase
#pragma unroll
      for (int p = 0; p < 2; ++p) {
        int c0 = (tx0 + 2 + p) * 64;
#pragma unroll
        for (int rep = 0; rep < 4; ++rep)
          fB[p][rep] = *(const float4*)&src_w[(long long)(r0 + hi + rep * 16) * C + c0 + cc];
      }
      __syncthreads();
#pragma unroll
      for (int p = 0; p < 2; ++p) {
        int c0 = (tx0 + p) * 64;
        bf16 outv[16] __attribute__((aligned(16)));
#pragma unroll
        for (int u = 0; u < 4; ++u) {
          int col = (16 * kk + 4 * u) ^ (((oc >> 4) & 3) << 2);
          *(bf16x4*)&outv[u * 4] = *(const bf16x4*)&t[p][oc * 68 + col];
        }
        bf16* dp = &dst[(long long)(c0 + oc) * R + r0 + 16 * kk];
        *(bf16x8*)dp       = *(const bf16x8*)&outv[0];
        *(bf16x8*)(dp + 8) = *(const bf16x8*)&outv[8];
      }
      __syncthreads();
#pragma unroll
      for (int p = 0; p < 2; ++p)
#pragma unroll
        for (int rep = 0; rep < 4; ++rep) {
          int rr = hi + rep * 16;
          float v[4] = {fB[p][rep].x, fB[p][rep].y, fB[p][rep].z, fB[p][rep].w};
#pragma unroll
          for (int i2 = 0; i2 < 4; ++i2) {
            int row = cc + i2;
            int col = rr ^ (((row >> 4) & 3) << 2);
            t[p][row * 68 + col] = (bf16)v[i2];
          }
        }
      __syncthreads();
#pragma unroll
      for (int p = 0; p < 2; ++p) {
        int c0 = (tx0 + 2 + p) * 64;
        bf16 outv[16] __attribute__((aligned(16)));
#pragma unroll
        for (int u = 0; u < 4; ++u) {
          int col = (16 * kk + 4 * u) ^ (((oc >> 4) & 3) << 2);
          *(bf16x4*)&outv[u * 4] = *(const bf16x4*)&t[p][oc * 68 + col];
        }
        bf16* dp = &dst[(long long)(c0 + oc) * R + r0 + 16 * kk];
        *(bf16x8*)dp       = *(const bf16x8*)&outv[0];
        *(bf16x8*)(dp + 8) = *(const bf16x8*)&outv[8];
      }
    }
  } else if (bid < 4032) {
    // ---- sinusoid ----
    int i = bid - 2496, m = tid;
    float p = (float)(1535 - i);
    float inv = expf(-((float)(2 * m) * (1.0f / 512.0f)) * 9.210340371976184f);
    float ang = p * inv;
    bf16x2 v = {(bf16)sinf(ang), (bf16)cosf(ang)};
    *(bf16x2*)&rb[(long long)i * 512 + 2 * m] = v;
  } else if (bid < 8128) {
    // ---- embed: 2 (row,e) pairs per block ----
    int rp = (bid - 4032) * 2 + (tid >> 7);
    int e2 = rp >> 12, row = rp & 4095;
    int t2 = tid & 127;
    int tok = e2 ? src[4095 - row] : src[row];
    long long base = ((long long)e2 * TOK + row) * 512 + t2 * 4;
    float4 f = *(const float4*)&emb[(long long)tok * 512 + t2 * 4];
    *(float4*)&Sf[base] = f;
    bf16 o[4] __attribute__((aligned(8))) = {(bf16)f.x, (bf16)f.y, (bf16)f.z, (bf16)f.w};
    *(bf16x4*)&Sb[base] = *(const bf16x4*)o;
  } else {
    // ---- zero_kv ----
    int idx = bid - 8128;
    int which = idx >> 11, e2 = (idx >> 10) & 1, r = idx & 1023;
    uint4 zv = {0u, 0u, 0u, 0u};
    if (which == 0) {
      if (tid < 64) ((uint4*)(kbuf + ((long long)e2 * KBROWS + r) * 512))[tid] = zv;
    } else if (r < 512) {
      if (tid < 128) ((uint4*)(vwoT + ((long long)e2 * 512 + r) * KBROWS))[tid] = zv;
    }
  }
}

// ---------------- residual + layernorm; outMode 1 = write final output directly ----------------
__global__ __launch_bounds__(64)
void ln_kernel(const float* Xf, const float* Tf, const float* lnA, const float* lnB,
               int gOff, bf16* OutB, float* OutF, int outMode, float* finalOut) {
  int row = blockIdx.x, e = blockIdx.y;
  long long base = ((long long)e * TOK + row) * 512;
  const float* ln = e ? lnB : lnA;
  int lane = threadIdx.x;
  int d0 = lane * 8;
  float4 x0 = *(const float4*)&Xf[base + d0];
  float4 x1 = *(const float4*)&Xf[base + d0 + 4];
  float4 t0 = *(const float4*)&Tf[base + d0];
  float4 t1 = *(const float4*)&Tf[base + d0 + 4];
  float vals[8] = {x0.x + t0.x, x0.y + t0.y, x0.z + t0.z, x0.w + t0.w,
                   x1.x + t1.x, x1.y + t1.y, x1.z + t1.z, x1.w + t1.w};
  float s = 0.f;
#pragma unroll
  for (int k = 0; k < 8; ++k) s += vals[k];
  for (int off = 32; off; off >>= 1) s += __shfl_xor(s, off);
  float mu = s * (1.0f / 512.0f);
  float vs = 0.f;
#pragma unroll
  for (int k = 0; k < 8; ++k) { float d = vals[k] - mu; vs += d * d; }
  for (int off = 32; off; off >>= 1) vs += __shfl_xor(vs, off);
  float rstd = rsqrtf(vs * (1.0f / 512.0f) + 1e-5f);
  float4 g0 = *(const float4*)&ln[gOff + d0];
  float4 g1 = *(const float4*)&ln[gOff + d0 + 4];
  float4 b0 = *(const float4*)&ln[gOff + 512 + d0];
  float4 b1 = *(const float4*)&ln[gOff + 512 + d0 + 4];
  float gm[8] = {g0.x, g0.y, g0.z, g0.w, g1.x, g1.y, g1.z, g1.w};
  float bt[8] = {b0.x, b0.y, b0.z, b0.w, b1.x, b1.y, b1.z, b1.w};
  float y[8];
#pragma unroll
  for (int k = 0; k < 8; ++k) y[k] = (vals[k] - mu) * rstd * gm[k] + bt[k];
  if (outMode == 0) {
    bf16 ob8[8] __attribute__((aligned(16)));
#pragma unroll
    for (int k = 0; k < 8; ++k) ob8[k] = (bf16)y[k];
    *(bf16x8*)&OutB[base + d0] = *(const bf16x8*)ob8;
    float4 ya = {y[0], y[1], y[2], y[3]}, yb = {y[4], y[5], y[6], y[7]};
    *(float4*)&OutF[base + d0]     = ya;
    *(float4*)&OutF[base + d0 + 4] = yb;
  } else {
    long long ob = e ? ((long long)(4095 - row) * 1024 + 512) : ((long long)row * 1024);
    float4 ya = {y[0], y[1], y[2], y[3]}, yb = {y[4], y[5], y[6], y[7]};
    *(float4*)&finalOut[ob + d0]     = ya;
    *(float4*)&finalOut[ob + d0 + 4] = yb;
  }
}

extern "C" void kernel_launch(void* const* d_in, const int* in_sizes, int n_in,
                              void* d_out, int out_size, void* d_ws, size_t ws_size,
                              hipStream_t stream) {
  const int*   src   = (const int*)d_in[0];
  const float* emb   = (const float*)d_in[2];
  const float* Wq_a  = (const float*)d_in[3];
  const float* Wo_a  = (const float*)d_in[4];
  const float* W1_a  = (const float*)d_in[5];
  const float* W2_a  = (const float*)d_in[6];
  const float* ln_a  = (const float*)d_in[7];
  const float* uv_a  = (const float*)d_in[8];
  const float* Wq_b  = (const float*)d_in[9];
  const float* Wo_b  = (const float*)d_in[10];
  const float* W1_b  = (const float*)d_in[11];
  const float* W2_b  = (const float*)d_in[12];
  const float* ln_b  = (const float*)d_in[13];
  const float* uv_b  = (const float*)d_in[14];
  float* out = (float*)d_out;

  char* w = (char*)d_ws;
  size_t off = 0;
  auto alloc = [&](long long elems, int esz) -> char* {
    char* p = w + off;
    off += (size_t)elems * esz;
    off = (off + 255) & ~(size_t)255;
    return p;
  };
  bf16* wqkvT = (bf16*)alloc(2LL * 6 * 1536 * 512, 2);  // rows: q, k, (wvo = Wv@Wo set at runtime)
  bf16* woT   = (bf16*)alloc(2LL * 6 * 512 * 512, 2);
  bf16* w1T   = (bf16*)alloc(2LL * 6 * 2048 * 512, 2);
  bf16* w2T   = (bf16*)alloc(2LL * 6 * 512 * 2048, 2);
  bf16* pk    = (bf16*)alloc(2LL * 6 * 1536 * 512, 2);
  bf16* Sb    = (bf16*)alloc(2LL * TOK * 512, 2);
  float* Sf   = (float*)alloc(2LL * TOK * 512, 4);
  bf16* quv   = (bf16*)alloc(2LL * TOK * 1024, 2);
  bf16* kbuf  = (bf16*)alloc(2LL * KBROWS * 512, 2);
  bf16* vwoT  = (bf16*)alloc(2LL * 512 * KBROWS, 2);
  bf16* P     = (bf16*)alloc(2LL * 8 * 512 * 1536, 2);
  float* t1f  = (float*)alloc(2LL * TOK * 512, 4);
  bf16* f1    = (bf16*)alloc(2LL * TOK * 2048, 2);
  // overlays (setup-only, inside f1's region; f1 first written in layer loop):
  bf16* rb      = f1;                          // 1.5 MB
  bf16* wrT     = f1 + 1024LL * 1024;          // 6 MB at +2MB
  bf16* wvPlain = f1 + 4096LL * 1024;          // 6 MB at +8MB

  if (off > ws_size) return;

  // ---- setup (single dispatch) ----
  setup_kernel<<<12224, 256, 0, stream>>>(Wq_a, Wq_b, Wo_a, Wo_b, W1_a, W1_b, W2_a, W2_b,
                                          wqkvT, wrT, wvPlain, woT, w1T, w2T,
                                          rb, src, emb, Sb, Sf, kbuf, vwoT);

  {  // pk[e][j] = R @ Wr[e][j]
    GemmArgs g = {};
    g.A = rb; g.sAe = 0; g.sAi = 0; g.ldA = 512;
    g.B = wrT; g.sBe = 0; g.sBi = 512LL * 512; g.ldB = 512;
    g.C = pk; g.sCe = 0; g.sCi = 1536LL * 512; g.ldC = 512;
    g.M = 1536; g.N = 512; g.K = 512; g.iPerE = 12;
    gemm_kernel<M_BF16, false, 128, 128><<<dim3(12, 4, 12), 256, 0, stream>>>(g);
  }
  {  // wvoT[e][j][od][k] = Wvo[k][od] = sum_v Wv[k][v] Wo[v][od]  -> wqkvT slot 2
    GemmArgs g = {};
    g.A = woT; g.sAe = 6LL * 262144; g.sAi = 262144; g.ldA = 512;       // A[od][v] = Wo[v][od]
    g.B = wvPlain; g.sBe = 6LL * 262144; g.sBi = 262144; g.ldB = 512;   // B[k][v]  = Wv[k][v]
    g.C = wqkvT + 2LL * 262144; g.sCe = 18LL * 262144; g.sCi = 3LL * 262144; g.ldC = 512;
    g.M = 512; g.N = 512; g.K = 512; g.iPerE = 6;
    gemm_kernel<M_BF16, false, 128, 128><<<dim3(4, 4, 12), 256, 0, stream>>>(g);
  }

  const float scale = 0.044194173824159216f;  // 1/sqrt(512)

  for (int j = 0; j < 6; ++j) {
    {  // QKV: q+u/q+v -> quv, k -> kbuf(+1024), S@Wvo -> vwoT(+1024, transposed)
      GemmArgs g = {};
      g.A = Sb; g.sAe = (long long)TOK * 512; g.sAi = 0; g.ldA = 512;
      g.B = wqkvT + (long long)j * 1536 * 512; g.sBe = 6LL * 1536 * 512; g.sBi = 0; g.ldB = 512;
      g.M = TOK; g.N = 1536; g.K = 512; g.iPerE = 1;
      g.quv = quv; g.kbuf = kbuf; g.vt = vwoT; g.uvA = uv_a; g.uvB = uv_b;
      gemm_kernel<M_QKV, false, 128, 128><<<dim3(32, 12, 2), 256, 0, stream>>>(g);
    }
    {  // P = exp(qu@Kwin^T + qv@pk^T scaled+masked)  (no-max softmax numerator)
      GemmArgs g = {};
      g.A = quv; g.sAe = (long long)TOK * 1024; g.sAi = 512LL * 1024; g.ldA = 1024;
      g.B = kbuf; g.sBe = (long long)KBROWS * 512; g.sBi = 512LL * 512; g.ldB = 512;
      g.B2 = pk + (long long)j * 1536 * 512; g.sB2e = 6LL * 1536 * 512; g.ldB2 = 512;
      g.C = P; g.sCe = 8LL * 512 * 1536; g.sCi = 512LL * 1536; g.ldC = 1536;
      g.M = 512; g.N = 1536; g.K = 1024; g.iPerE = 8;
      g.scale = scale;
      gemm_kernel<M_SCOREXP, true, 128, 128><<<dim3(4, 12, 16), 256, 0, stream>>>(g);
    }
    {  // attn_proj = (P @ VWowin) / rowsum(P)  -> fp32 t1f
      GemmArgs g = {};
      g.A = P; g.sAe = 8LL * 512 * 1536; g.sAi = 512LL * 1536; g.ldA = 1536;
      g.B = vwoT; g.sBe = 512LL * KBROWS; g.sBi = 512; g.ldB = KBROWS;
      g.Cf = t1f; g.sCe = (long long)TOK * 512; g.sCi = 512LL * 512; g.ldC = 512;
      g.M = 512; g.N = 512; g.K = 1536; g.iPerE = 8;
      gemm_kernel<M_PV, false, 64, 128><<<dim3(8, 4, 16), 256, 0, stream>>>(g);
    }
    // H = LN(state + attn_out) — in-place into Sb/Sf
    ln_kernel<<<dim3(4096, 2), 64, 0, stream>>>(Sf, t1f, ln_a, ln_b, (j * 4 + 0) * 512, Sb, Sf, 0, out);
    {  // F1 = relu(H @ W1)
      GemmArgs g = {};
      g.A = Sb; g.sAe = (long long)TOK * 512; g.sAi = 0; g.ldA = 512;
      g.B = w1T + (long long)j * 2048 * 512; g.sBe = 6LL * 2048 * 512; g.sBi = 0; g.ldB = 512;
      g.C = f1; g.sCe = (long long)TOK * 2048; g.sCi = 0; g.ldC = 2048;
      g.M = TOK; g.N = 2048; g.K = 512; g.iPerE = 1;
      gemm_kernel<M_RELU, false, 128, 128><<<dim3(32, 16, 2), 256, 0, stream>>>(g);
    }
    {  // T1 = F1 @ W2 (fp32 out)
      GemmArgs g = {};
      g.A = f1; g.sAe = (long long)TOK * 2048; g.sAi = 0; g.ldA = 2048;
      g.B = w2T + (long long)j * 512 * 2048; g.sBe = 6LL * 512 * 2048; g.sBi = 0; g.ldB = 2048;
      g.Cf = t1f; g.sCe = (long long)TOK * 512; g.sCi = 0; g.ldC = 512;
      g.M = TOK; g.N = 512; g.K = 2048; g.iPerE = 1;
      gemm_kernel<M_F32, false, 64, 128><<<dim3(64, 4, 2), 256, 0, stream>>>(g);
    }
    // state = LN(H + ff); last layer writes final output directly (concat + reverse fused)
    ln_kernel<<<dim3(4096, 2), 64, 0, stream>>>(Sf, t1f, ln_a, ln_b, (j * 4 + 2) * 512, Sb, Sf,
                                                (j == 5) ? 1 : 0, out);
  }
}

// Round 4
// 1175.458 us; speedup vs baseline: 1.1147x; 1.0573x over previous
//
#include <hip/hip_runtime.h>

typedef __bf16 bf16;
typedef __bf16 bf16x8 __attribute__((ext_vector_type(8)));
typedef __bf16 bf16x4 __attribute__((ext_vector_type(4)));
typedef __bf16 bf16x2 __attribute__((ext_vector_type(2)));
typedef float f32x4 __attribute__((ext_vector_type(4)));

typedef __attribute__((address_space(3))) void lds_void_t;
typedef const __attribute__((address_space(1))) void gbl_void_t;

#define TOK 4096
#define KBROWS 5120

enum { M_BF16 = 0, M_F32 = 1, M_RELU = 2, M_QKV = 3, M_SCOREXP = 4, M_PV = 5 };

struct GemmArgs {
  const bf16* A; long long sAe, sAi; int ldA;
  const bf16* B; long long sBe, sBi; int ldB;
  const bf16* B2; long long sB2e; int ldB2;
  bf16* C; float* Cf; long long sCe, sCi; int ldC;
  int M, N, K, iPerE;
  bf16 *quv, *kbuf, *vt;
  const float *uvA, *uvB;
  float scale;
};

// ---------------- GEMM: C = A @ B^T, A (MxK) row-major, B (NxK) row-major ----------------
// Staging via global_load_lds; lane (8r+c) fetches chunk c^r -> XOR-swizzled LDS, frag reads
// sw=(4s+quad)^l7 are 0-bank-conflict. M_SCOREXP: epilogue exp (bounded logits, mask->0);
// fully-masked blocks (tn+TN<=T, T mult of 512) early-return — P pre-zeroed once in setup.
// M_PV: skips K<kstart (those P cols are exact zeros); row-sum l computed in-loop, /l in epi.
// M_QKV region 2 (vt transposed scatter): routed through LDS with involution swizzle.
template<int MODE, bool SPLITB, int TM, int TN>
__global__ __launch_bounds__(256, 4)
void gemm_kernel(GemmArgs g) {
  constexpr int FA = TM / 32, FB = TN / 32;
  int z = blockIdx.z;
  int e = z / g.iPerE;
  int i = z % g.iPerE;

  int tm = blockIdx.x * TM;
  int tn = blockIdx.y * TN;

  if constexpr (MODE == M_SCOREXP) {
    int T = 1024 - ((i < 2 ? i : 2) << 9);
    if (tn + TN <= T) return;   // fully masked tile: P already zero (setup), PV skips it
  }

  const bf16* A = g.A + e * g.sAe + i * g.sAi;
  const bf16* B = g.B + e * g.sBe + i * g.sBi;
  const bf16* B2 = nullptr;
  if constexpr (SPLITB) B2 = g.B2 + e * g.sB2e;

  __shared__ uint4 smem[TM * 8 + TN * 8];
  uint4* As4 = smem;
  uint4* Bs4 = smem + TM * 8;
  __shared__ float ls[MODE == M_PV ? TM : 1];
  bf16* As_lds = (bf16*)As4;
  bf16* Bs_lds = (bf16*)Bs4;

  int tid = threadIdx.x;
  int wave = tid >> 6, lane = tid & 63;
  int wm = (wave >> 1) * (TM / 2), wn = (wave & 1) * (TN / 2);
  int quad = lane >> 4, l15 = lane & 15;
  int l7 = l15 & 7;
  int l8r = lane >> 3, l8c = lane & 7;
  int fc = l8c ^ l8r;

  f32x4 acc[FA][FB] = {};
  float lreg[FA];
#pragma unroll
  for (int t = 0; t < FA; ++t) lreg[t] = 0.f;

  int kstart = 0;
  if constexpr (MODE == M_PV) kstart = (i < 2) ? (2 - i) << 9 : 0;  // P cols < kstart are 0

  for (int k0 = kstart; k0 < g.K; k0 += 64) {
#pragma unroll
    for (int ii = 0; ii < FA; ++ii) {
      int rowbase = (wave * FA + ii) * 8;
      int r = rowbase + l8r;
      const bf16* gp = &A[(long long)(tm + r) * g.ldA + k0 + fc * 8];
      __builtin_amdgcn_global_load_lds((gbl_void_t*)gp, (lds_void_t*)&As_lds[rowbase * 64], 16, 0, 0);
    }
#pragma unroll
    for (int ii = 0; ii < FB; ++ii) {
      int rowbase = (wave * FB + ii) * 8;
      int r = rowbase + l8r;
      const bf16* gp;
      if constexpr (SPLITB) {
        int kk = k0 + fc * 8;
        gp = (kk < 512) ? &B[(long long)(tn + r) * g.ldB + kk]
                        : &B2[(long long)(tn + r) * g.ldB2 + (kk - 512)];
      } else {
        gp = &B[(long long)(tn + r) * g.ldB + k0 + fc * 8];
      }
      __builtin_amdgcn_global_load_lds((gbl_void_t*)gp, (lds_void_t*)&Bs_lds[rowbase * 64], 16, 0, 0);
    }
    __syncthreads();
#pragma unroll
    for (int s = 0; s < 2; ++s) {
      int sw = (s * 4 + quad) ^ l7;
      bf16x8 af[FA], bfr[FB];
#pragma unroll
      for (int t = 0; t < FA; ++t) af[t]  = ((const bf16x8*)As4)[(wm + t * 16 + l15) * 8 + sw];
#pragma unroll
      for (int t = 0; t < FB; ++t) bfr[t] = ((const bf16x8*)Bs4)[(wn + t * 16 + l15) * 8 + sw];
      if constexpr (MODE == M_PV) {
#pragma unroll
        for (int t = 0; t < FA; ++t)
#pragma unroll
          for (int q2 = 0; q2 < 8; ++q2) lreg[t] += (float)af[t][q2];
      }
#pragma unroll
      for (int a = 0; a < FA; ++a)
#pragma unroll
        for (int b = 0; b < FB; ++b)
          acc[a][b] = __builtin_amdgcn_mfma_f32_16x16x32_bf16(af[a], bfr[b], acc[a][b], 0, 0, 0);
    }
    __syncthreads();
  }

  if constexpr (MODE == M_PV) {
    // rowsum l: lane holds partial of row (wm + t*16 + l15); reduce across quads
#pragma unroll
    for (int t = 0; t < FA; ++t) {
      lreg[t] += __shfl_xor(lreg[t], 16);
      lreg[t] += __shfl_xor(lreg[t], 32);
      if (quad == 0) ls[wm + t * 16 + l15] = lreg[t];
    }
    __syncthreads();
  }

  // epilogues. C/D layout: col = lane&15, row = quad*4 + reg (m89-verified)
  if constexpr (MODE == M_QKV) {
    const float* uv = e ? g.uvB : g.uvA;
    int region = tn >> 9;   // block-uniform: TN=128 tiles never span a 512-col region
    if (region == 2) {
      // S@Wvo -> vwoT[od][1024+token]: transpose through LDS (smem free after K-loop barrier)
      bf16* sm = (bf16*)smem;   // 128x128 bf16 (requires TM==TN==128)
#pragma unroll
      for (int a = 0; a < FA; ++a) {
        int m_l = wm + a * 16 + quad * 4;
#pragma unroll
        for (int b = 0; b < FB; ++b) {
          int c_l = wn + b * 16 + l15;
          int mp = m_l ^ ((c_l & 15) << 3);
          bf16 v4[4] __attribute__((aligned(8)));
#pragma unroll
          for (int r = 0; r < 4; ++r) v4[r] = (bf16)acc[a][b][r];
          *(bf16x4*)&sm[c_l * 128 + mp] = *(const bf16x4*)v4;
        }
      }
      __syncthreads();
      int c_l = tid >> 1;
      int half = (tid & 1) * 64;
      long long vb = (long long)e * 512 * KBROWS + (long long)(tn - 1024 + c_l) * KBROWS + 1024 + tm;
#pragma unroll
      for (int u = 0; u < 8; ++u) {
        int m0 = half + u * 8;
        int mp = m0 ^ ((c_l & 15) << 3);
        *(bf16x8*)&g.vt[vb + m0] = *(const bf16x8*)&sm[c_l * 128 + mp];
      }
    } else if (region == 0) {
#pragma unroll
      for (int a = 0; a < FA; ++a) {
        int mB = tm + wm + a * 16 + quad * 4;
#pragma unroll
        for (int b = 0; b < FB; ++b) {
          int cin = tn + wn + b * 16 + l15;
          float u0 = uv[cin], v0 = uv[512 + cin];
#pragma unroll
          for (int r = 0; r < 4; ++r) {
            int m = mB + r;
            float val = acc[a][b][r];
            long long qb = (long long)e * TOK * 1024 + (long long)m * 1024;
            g.quv[qb + cin]       = (bf16)(val + u0);
            g.quv[qb + 512 + cin] = (bf16)(val + v0);
          }
        }
      }
    } else {
#pragma unroll
      for (int a = 0; a < FA; ++a) {
        int mB = tm + wm + a * 16 + quad * 4;
#pragma unroll
        for (int b = 0; b < FB; ++b) {
          int cin = (tn - 512) + wn + b * 16 + l15;
#pragma unroll
          for (int r = 0; r < 4; ++r)
            g.kbuf[(long long)e * KBROWS * 512 + (long long)(1024 + mB + r) * 512 + cin] =
                (bf16)acc[a][b][r];
        }
      }
    }
  } else if constexpr (MODE == M_SCOREXP) {
    bf16* C = g.C + e * g.sCe + i * g.sCi;
    int T = 1024 - ((i < 2 ? i : 2) << 9);   // mask cols < T
#pragma unroll
    for (int a = 0; a < FA; ++a) {
      int mB = tm + wm + a * 16 + quad * 4;
#pragma unroll
      for (int b = 0; b < FB; ++b) {
        int col = tn + wn + b * 16 + l15;
        float bias = (col < T) ? -1e9f : 0.0f;
#pragma unroll
        for (int r = 0; r < 4; ++r)
          C[(long long)(mB + r) * g.ldC + col] = (bf16)__expf(acc[a][b][r] * g.scale + bias);
      }
    }
  } else if constexpr (MODE == M_PV) {
    float* Cf = g.Cf + e * g.sCe + i * g.sCi;
#pragma unroll
    for (int a = 0; a < FA; ++a) {
      int lrow = wm + a * 16 + quad * 4;
      int mB = tm + lrow;
#pragma unroll
      for (int b = 0; b < FB; ++b) {
        int col = tn + wn + b * 16 + l15;
#pragma unroll
        for (int r = 0; r < 4; ++r)
          Cf[(long long)(mB + r) * g.ldC + col] = acc[a][b][r] / ls[lrow + r];
      }
    }
  } else {
#pragma unroll
    for (int a = 0; a < FA; ++a) {
      int mB = tm + wm + a * 16 + quad * 4;
#pragma unroll
      for (int b = 0; b < FB; ++b) {
        int col = tn + wn + b * 16 + l15;
#pragma unroll
        for (int r = 0; r < 4; ++r) {
          float val = acc[a][b][r];
          if constexpr (MODE == M_RELU) val = val > 0.f ? val : 0.f;
          if constexpr (MODE == M_F32) {
            float* Cf = g.Cf + e * g.sCe + i * g.sCi;
            Cf[(long long)(mB + r) * g.ldC + col] = val;
          } else {
            bf16* C = g.C + e * g.sCe + i * g.sCi;
            C[(long long)(mB + r) * g.ldC + col] = (bf16)val;
          }
        }
      }
    }
  }
}

// ---------------- unified setup: weight prep + sinusoid + embed + zero_kv + zero_P ----------------
__device__ inline void prep_locate(int id, const float* qa, const float* qb,
                                   const float* oa, const float* ob,
                                   const float* w1a, const float* w1b,
                                   const float* w2a, const float* w2b,
                                   bf16* wqkvT, bf16* wrT, bf16* wvPlain, bf16* woT,
                                   bf16* w1T, bf16* w2T,
                                   const float*& src, bf16*& dst, int& R, int& C,
                                   int& tx, int& ty, bool& plain) {
  plain = false;
  if (id < 3072) {          // Wqkvr: 48 mats x 64 tiles
    int mat = id >> 6, tile = id & 63;
    tx = tile & 7; ty = tile >> 3;
    int e = mat / 24, rj = mat % 24, j = rj >> 2, c = rj & 3;
    src = (e ? qb : qa) + (long long)(j * 4 + c) * 262144;
    R = 512; C = 512;
    if (c < 2)        dst = wqkvT + ((long long)(e * 6 + j) * 3 + c) * 262144;
    else if (c == 2) { dst = wvPlain + (long long)(e * 6 + j) * 262144; plain = true; }
    else              dst = wrT + (long long)(e * 6 + j) * 262144;
  } else if (id < 3840) {   // Wo: 12 mats x 64 tiles
    int id2 = id - 3072; int mat = id2 >> 6, tile = id2 & 63;
    tx = tile & 7; ty = tile >> 3;
    int e = mat / 6, j = mat % 6;
    src = (e ? ob : oa) + (long long)j * 262144;
    dst = woT + (long long)mat * 262144; R = 512; C = 512;
  } else if (id < 6912) {   // W1 (512x2048): 12 mats x 256 tiles
    int id2 = id - 3840; int mat = id2 >> 8, tile = id2 & 255;
    tx = tile & 31; ty = tile >> 5;
    int e = mat / 6, j = mat % 6;
    src = (e ? w1b : w1a) + (long long)j * 512 * 2048;
    dst = w1T + (long long)mat * 512 * 2048; R = 512; C = 2048;
  } else {                  // W2 (2048x512): 12 mats x 256 tiles
    int id2 = id - 6912; int mat = id2 >> 8, tile = id2 & 255;
    tx = tile & 7; ty = tile >> 3;
    int e = mat / 6, j = mat % 6;
    src = (e ? w2b : w2a) + (long long)j * 2048 * 512;
    dst = w2T + (long long)mat * 2048 * 512; R = 2048; C = 512;
  }
}

// block-id ranges: [0,2496) prep (4 tiles each) | [2496,4032) sinusoid |
//  [4032,8128) embed (2 rows) | [8128,12224) zero_kv | [12224,14272) zero masked P regions
__global__ __launch_bounds__(256)
void setup_kernel(const float* qa, const float* qb, const float* oa, const float* ob,
                  const float* w1a, const float* w1b, const float* w2a, const float* w2b,
                  bf16* wqkvT, bf16* wrT, bf16* wvPlain, bf16* woT, bf16* w1T, bf16* w2T,
                  bf16* rb, const int* src, const float* emb, bf16* Sb, float* Sf,
                  bf16* kbuf, bf16* vwoT, bf16* P) {
  __shared__ bf16 t[2][64 * 68];
  int bid = blockIdx.x;
  int tid = threadIdx.x;

  if (bid < 2496) {
    // ---- weight prep: 4 adjacent col-tiles (same mat/rows; boundaries all %4==0) ----
    int id0 = bid * 4;
    const float* src_w; bf16* dst; int R, C, tx0, ty; bool plain;
    prep_locate(id0, qa, qb, oa, ob, w1a, w1b, w2a, w2b,
                wqkvT, wrT, wvPlain, woT, w1T, w2T, src_w, dst, R, C, tx0, ty, plain);
    int r0 = ty * 64;

    if (plain) {
      int c8 = (tid & 7) * 8;
      int r8 = tid >> 3;                       // 0..31
      float4 f[4][4];
#pragma unroll
      for (int p = 0; p < 4; ++p) {
        int c0 = (tx0 + p) * 64;
#pragma unroll
        for (int rep = 0; rep < 2; ++rep) {
          const float* sp = &src_w[(long long)(r0 + r8 + rep * 32) * C + c0 + c8];
          f[p][rep * 2]     = *(const float4*)sp;
          f[p][rep * 2 + 1] = *(const float4*)(sp + 4);
        }
      }
#pragma unroll
      for (int p = 0; p < 4; ++p) {
        int c0 = (tx0 + p) * 64;
#pragma unroll
        for (int rep = 0; rep < 2; ++rep) {
          float4 f0 = f[p][rep * 2], f1 = f[p][rep * 2 + 1];
          bf16 o[8] __attribute__((aligned(16))) =
            {(bf16)f0.x, (bf16)f0.y, (bf16)f0.z, (bf16)f0.w,
             (bf16)f1.x, (bf16)f1.y, (bf16)f1.z, (bf16)f1.w};
          *(bf16x8*)&dst[(long long)(r0 + r8 + rep * 32) * C + c0 + c8] = *(const bf16x8*)o;
        }
      }
    } else {
      // two pairs through the same 2-buffer LDS; pair-B loads issued during pair-A store phase
      int l15 = tid & 15;                      // src-col group
      int hi  = tid >> 4;                      // 0..15 src-row
      int cc = l15 * 4;
      int oc = tid >> 2;                       // output row (src col) 0..63
      int kk = tid & 3;                        // 16-elem chunk
      float4 fA[2][4], fB[2][4];
#pragma unroll
      for (int p = 0; p < 2; ++p) {
        int c0 = (tx0 + p) * 64;
#pragma unroll
        for (int rep = 0; rep < 4; ++rep)
          fA[p][rep] = *(const float4*)&src_w[(long long)(r0 + hi + rep * 16) * C + c0 + cc];
      }
#pragma unroll
      for (int p = 0; p < 2; ++p)
#pragma unroll
        for (int rep = 0; rep < 4; ++rep) {
          int rr = hi + rep * 16;
          float v[4] = {fA[p][rep].x, fA[p][rep].y, fA[p][rep].z, fA[p][rep].w};
#pragma unroll
          for (int i2 = 0; i2 < 4; ++i2) {
            int row = cc + i2;
            int col = rr ^ (((row >> 4) & 3) << 2);
            t[p][row * 68 + col] = (bf16)v[i2];
          }
        }
      // issue pair-B loads before the barrier: latency hides under pair-A's store phase
#pragma unroll
      for (int p = 0; p < 2; ++p) {
        int c0 = (tx0 + 2 + p) * 64;
#pragma unroll
        for (int rep = 0; rep < 4; ++rep)
          fB[p][rep] = *(const float4*)&src_w[(long long)(r0 + hi + rep * 16) * C + c0 + cc];
      }
      __syncthreads();
#pragma unroll
      for (int p = 0; p < 2; ++p) {
        int c0 = (tx0 + p) * 64;
        bf16 outv[16] __attribute__((aligned(16)));
#pragma unroll
        for (int u = 0; u < 4; ++u) {
          int col = (16 * kk + 4 * u) ^ (((oc >> 4) & 3) << 2);
          *(bf16x4*)&outv[u * 4] = *(const bf16x4*)&t[p][oc * 68 + col];
        }
        bf16* dp = &dst[(long long)(c0 + oc) * R + r0 + 16 * kk];
        *(bf16x8*)dp       = *(const bf16x8*)&outv[0];
        *(bf16x8*)(dp + 8) = *(const bf16x8*)&outv[8];
      }
      __syncthreads();
#pragma unroll
      for (int p = 0; p < 2; ++p)
#pragma unroll
        for (int rep = 0; rep < 4; ++rep) {
          int rr = hi + rep * 16;
          float v[4] = {fB[p][rep].x, fB[p][rep].y, fB[p][rep].z, fB[p][rep].w};
#pragma unroll
          for (int i2 = 0; i2 < 4; ++i2) {
            int row = cc + i2;
            int col = rr ^ (((row >> 4) & 3) << 2);
            t[p][row * 68 + col] = (bf16)v[i2];
          }
        }
      __syncthreads();
#pragma unroll
      for (int p = 0; p < 2; ++p) {
        int c0 = (tx0 + 2 + p) * 64;
        bf16 outv[16] __attribute__((aligned(16)));
#pragma unroll
        for (int u = 0; u < 4; ++u) {
          int col = (16 * kk + 4 * u) ^ (((oc >> 4) & 3) << 2);
          *(bf16x4*)&outv[u * 4] = *(const bf16x4*)&t[p][oc * 68 + col];
        }
        bf16* dp = &dst[(long long)(c0 + oc) * R + r0 + 16 * kk];
        *(bf16x8*)dp       = *(const bf16x8*)&outv[0];
        *(bf16x8*)(dp + 8) = *(const bf16x8*)&outv[8];
      }
    }
  } else if (bid < 4032) {
    // ---- sinusoid ----
    int i = bid - 2496, m = tid;
    float p = (float)(1535 - i);
    float inv = expf(-((float)(2 * m) * (1.0f / 512.0f)) * 9.210340371976184f);
    float ang = p * inv;
    bf16x2 v = {(bf16)sinf(ang), (bf16)cosf(ang)};
    *(bf16x2*)&rb[(long long)i * 512 + 2 * m] = v;
  } else if (bid < 8128) {
    // ---- embed: 2 (row,e) pairs per block ----
    int rp = (bid - 4032) * 2 + (tid >> 7);
    int e2 = rp >> 12, row = rp & 4095;
    int t2 = tid & 127;
    int tok = e2 ? src[4095 - row] : src[row];
    long long base = ((long long)e2 * TOK + row) * 512 + t2 * 4;
    float4 f = *(const float4*)&emb[(long long)tok * 512 + t2 * 4];
    *(float4*)&Sf[base] = f;
    bf16 o[4] __attribute__((aligned(8))) = {(bf16)f.x, (bf16)f.y, (bf16)f.z, (bf16)f.w};
    *(bf16x4*)&Sb[base] = *(const bf16x4*)o;
  } else if (bid < 12224) {
    // ---- zero_kv ----
    int idx = bid - 8128;
    int which = idx >> 11, e2 = (idx >> 10) & 1, r = idx & 1023;
    uint4 zv = {0u, 0u, 0u, 0u};
    if (which == 0) {
      if (tid < 64) ((uint4*)(kbuf + ((long long)e2 * KBROWS + r) * 512))[tid] = zv;
    } else if (r < 512) {
      if (tid < 128) ((uint4*)(vwoT + ((long long)e2 * 512 + r) * KBROWS))[tid] = zv;
    }
  } else {
    // ---- zero masked P regions (written once; SCOREXP skips these tiles every layer) ----
    // seg 0: rows 0..511 cols 0..1023; seg 1: rows 0..511 cols 0..511 (per encoder)
    int idx = bid - 12224;                 // [0, 2048)
    int e2 = idx >> 10, rr = idx & 1023;
    uint4 zv = {0u, 0u, 0u, 0u};
    long long sCe = 8LL * 512 * 1536, sCi = 512LL * 1536;
    if (rr < 512) {            // seg 0 row rr, 1024 cols = 128 uint4
      if (tid < 128) ((uint4*)(P + e2 * sCe + 0 * sCi + (long long)rr * 1536))[tid] = zv;
    } else {                   // seg 1 row rr-512, 512 cols = 64 uint4
      if (tid < 64) ((uint4*)(P + e2 * sCe + 1 * sCi + (long long)(rr - 512) * 1536))[tid] = zv;
    }
  }
}

// ---------------- residual + layernorm; outMode 1 = write final output directly ----------------
// v3: 256 threads, 4 rows per block (one independent wave per row)
__global__ __launch_bounds__(256)
void ln_kernel(const float* Xf, const float* Tf, const float* lnA, const float* lnB,
               int gOff, bf16* OutB, float* OutF, int outMode, float* finalOut) {
  int wave = threadIdx.x >> 6;
  int row = blockIdx.x * 4 + wave, e = blockIdx.y;
  long long base = ((long long)e * TOK + row) * 512;
  const float* ln = e ? lnB : lnA;
  int lane = threadIdx.x & 63;
  int d0 = lane * 8;
  float4 x0 = *(const float4*)&Xf[base + d0];
  float4 x1 = *(const float4*)&Xf[base + d0 + 4];
  float4 t0 = *(const float4*)&Tf[base + d0];
  float4 t1 = *(const float4*)&Tf[base + d0 + 4];
  float vals[8] = {x0.x + t0.x, x0.y + t0.y, x0.z + t0.z, x0.w + t0.w,
                   x1.x + t1.x, x1.y + t1.y, x1.z + t1.z, x1.w + t1.w};
  float s = 0.f;
#pragma unroll
  for (int k = 0; k < 8; ++k) s += vals[k];
  for (int off = 32; off; off >>= 1) s += __shfl_xor(s, off);
  float mu = s * (1.0f / 512.0f);
  float vs = 0.f;
#pragma unroll
  for (int k = 0; k < 8; ++k) { float d = vals[k] - mu; vs += d * d; }
  for (int off = 32; off; off >>= 1) vs += __shfl_xor(vs, off);
  float rstd = rsqrtf(vs * (1.0f / 512.0f) + 1e-5f);
  float4 g0 = *(const float4*)&ln[gOff + d0];
  float4 g1 = *(const float4*)&ln[gOff + d0 + 4];
  float4 b0 = *(const float4*)&ln[gOff + 512 + d0];
  float4 b1 = *(const float4*)&ln[gOff + 512 + d0 + 4];
  float gm[8] = {g0.x, g0.y, g0.z, g0.w, g1.x, g1.y, g1.z, g1.w};
  float bt[8] = {b0.x, b0.y, b0.z, b0.w, b1.x, b1.y, b1.z, b1.w};
  float y[8];
#pragma unroll
  for (int k = 0; k < 8; ++k) y[k] = (vals[k] - mu) * rstd * gm[k] + bt[k];
  if (outMode == 0) {
    bf16 ob8[8] __attribute__((aligned(16)));
#pragma unroll
    for (int k = 0; k < 8; ++k) ob8[k] = (bf16)y[k];
    *(bf16x8*)&OutB[base + d0] = *(const bf16x8*)ob8;
    float4 ya = {y[0], y[1], y[2], y[3]}, yb = {y[4], y[5], y[6], y[7]};
    *(float4*)&OutF[base + d0]     = ya;
    *(float4*)&OutF[base + d0 + 4] = yb;
  } else {
    long long ob = e ? ((long long)(4095 - row) * 1024 + 512) : ((long long)row * 1024);
    float4 ya = {y[0], y[1], y[2], y[3]}, yb = {y[4], y[5], y[6], y[7]};
    *(float4*)&finalOut[ob + d0]     = ya;
    *(float4*)&finalOut[ob + d0 + 4] = yb;
  }
}

extern "C" void kernel_launch(void* const* d_in, const int* in_sizes, int n_in,
                              void* d_out, int out_size, void* d_ws, size_t ws_size,
                              hipStream_t stream) {
  const int*   src   = (const int*)d_in[0];
  const float* emb   = (const float*)d_in[2];
  const float* Wq_a  = (const float*)d_in[3];
  const float* Wo_a  = (const float*)d_in[4];
  const float* W1_a  = (const float*)d_in[5];
  const float* W2_a  = (const float*)d_in[6];
  const float* ln_a  = (const float*)d_in[7];
  const float* uv_a  = (const float*)d_in[8];
  const float* Wq_b  = (const float*)d_in[9];
  const float* Wo_b  = (const float*)d_in[10];
  const float* W1_b  = (const float*)d_in[11];
  const float* W2_b  = (const float*)d_in[12];
  const float* ln_b  = (const float*)d_in[13];
  const float* uv_b  = (const float*)d_in[14];
  float* out = (float*)d_out;

  char* w = (char*)d_ws;
  size_t off = 0;
  auto alloc = [&](long long elems, int esz) -> char* {
    char* p = w + off;
    off += (size_t)elems * esz;
    off = (off + 255) & ~(size_t)255;
    return p;
  };
  bf16* wqkvT = (bf16*)alloc(2LL * 6 * 1536 * 512, 2);  // rows: q, k, (wvo = Wv@Wo set at runtime)
  bf16* woT   = (bf16*)alloc(2LL * 6 * 512 * 512, 2);
  bf16* w1T   = (bf16*)alloc(2LL * 6 * 2048 * 512, 2);
  bf16* w2T   = (bf16*)alloc(2LL * 6 * 512 * 2048, 2);
  bf16* pk    = (bf16*)alloc(2LL * 6 * 1536 * 512, 2);
  bf16* Sb    = (bf16*)alloc(2LL * TOK * 512, 2);
  float* Sf   = (float*)alloc(2LL * TOK * 512, 4);
  bf16* quv   = (bf16*)alloc(2LL * TOK * 1024, 2);
  bf16* kbuf  = (bf16*)alloc(2LL * KBROWS * 512, 2);
  bf16* vwoT  = (bf16*)alloc(2LL * 512 * KBROWS, 2);
  bf16* P     = (bf16*)alloc(2LL * 8 * 512 * 1536, 2);
  float* t1f  = (float*)alloc(2LL * TOK * 512, 4);
  bf16* f1    = (bf16*)alloc(2LL * TOK * 2048, 2);
  // overlays (setup-only, inside f1's region; f1 first written in layer loop):
  bf16* rb      = f1;                          // 1.5 MB
  bf16* wrT     = f1 + 1024LL * 1024;          // 6 MB at +2MB
  bf16* wvPlain = f1 + 4096LL * 1024;          // 6 MB at +8MB

  if (off > ws_size) return;

  // ---- setup (single dispatch) ----
  setup_kernel<<<14272, 256, 0, stream>>>(Wq_a, Wq_b, Wo_a, Wo_b, W1_a, W1_b, W2_a, W2_b,
                                          wqkvT, wrT, wvPlain, woT, w1T, w2T,
                                          rb, src, emb, Sb, Sf, kbuf, vwoT, P);

  {  // pk[e][j] = R @ Wr[e][j]
    GemmArgs g = {};
    g.A = rb; g.sAe = 0; g.sAi = 0; g.ldA = 512;
    g.B = wrT; g.sBe = 0; g.sBi = 512LL * 512; g.ldB = 512;
    g.C = pk; g.sCe = 0; g.sCi = 1536LL * 512; g.ldC = 512;
    g.M = 1536; g.N = 512; g.K = 512; g.iPerE = 12;
    gemm_kernel<M_BF16, false, 128, 128><<<dim3(12, 4, 12), 256, 0, stream>>>(g);
  }
  {  // wvoT[e][j][od][k] = Wvo[k][od] = sum_v Wv[k][v] Wo[v][od]  -> wqkvT slot 2
    GemmArgs g = {};
    g.A = woT; g.sAe = 6LL * 262144; g.sAi = 262144; g.ldA = 512;       // A[od][v] = Wo[v][od]
    g.B = wvPlain; g.sBe = 6LL * 262144; g.sBi = 262144; g.ldB = 512;   // B[k][v]  = Wv[k][v]
    g.C = wqkvT + 2LL * 262144; g.sCe = 18LL * 262144; g.sCi = 3LL * 262144; g.ldC = 512;
    g.M = 512; g.N = 512; g.K = 512; g.iPerE = 6;
    gemm_kernel<M_BF16, false, 128, 128><<<dim3(4, 4, 12), 256, 0, stream>>>(g);
  }

  const float scale = 0.044194173824159216f;  // 1/sqrt(512)

  for (int j = 0; j < 6; ++j) {
    {  // QKV: q+u/q+v -> quv, k -> kbuf(+1024), S@Wvo -> vwoT(+1024, transposed)
      GemmArgs g = {};
      g.A = Sb; g.sAe = (long long)TOK * 512; g.sAi = 0; g.ldA = 512;
      g.B = wqkvT + (long long)j * 1536 * 512; g.sBe = 6LL * 1536 * 512; g.sBi = 0; g.ldB = 512;
      g.M = TOK; g.N = 1536; g.K = 512; g.iPerE = 1;
      g.quv = quv; g.kbuf = kbuf; g.vt = vwoT; g.uvA = uv_a; g.uvB = uv_b;
      gemm_kernel<M_QKV, false, 128, 128><<<dim3(32, 12, 2), 256, 0, stream>>>(g);
    }
    {  // P = exp(qu@Kwin^T + qv@pk^T scaled+masked)  (no-max softmax numerator)
      GemmArgs g = {};
      g.A = quv; g.sAe = (long long)TOK * 1024; g.sAi = 512LL * 1024; g.ldA = 1024;
      g.B = kbuf; g.sBe = (long long)KBROWS * 512; g.sBi = 512LL * 512; g.ldB = 512;
      g.B2 = pk + (long long)j * 1536 * 512; g.sB2e = 6LL * 1536 * 512; g.ldB2 = 512;
      g.C = P; g.sCe = 8LL * 512 * 1536; g.sCi = 512LL * 1536; g.ldC = 1536;
      g.M = 512; g.N = 1536; g.K = 1024; g.iPerE = 8;
      g.scale = scale;
      gemm_kernel<M_SCOREXP, true, 128, 128><<<dim3(4, 12, 16), 256, 0, stream>>>(g);
    }
    {  // attn_proj = (P @ VWowin) / rowsum(P)  -> fp32 t1f
      GemmArgs g = {};
      g.A = P; g.sAe = 8LL * 512 * 1536; g.sAi = 512LL * 1536; g.ldA = 1536;
      g.B = vwoT; g.sBe = 512LL * KBROWS; g.sBi = 512; g.ldB = KBROWS;
      g.Cf = t1f; g.sCe = (long long)TOK * 512; g.sCi = 512LL * 512; g.ldC = 512;
      g.M = 512; g.N = 512; g.K = 1536; g.iPerE = 8;
      gemm_kernel<M_PV, false, 64, 128><<<dim3(8, 4, 16), 256, 0, stream>>>(g);
    }
    // H = LN(state + attn_out) — in-place into Sb/Sf
    ln_kernel<<<dim3(1024, 2), 256, 0, stream>>>(Sf, t1f, ln_a, ln_b, (j * 4 + 0) * 512, Sb, Sf, 0, out);
    {  // F1 = relu(H @ W1)
      GemmArgs g = {};
      g.A = Sb; g.sAe = (long long)TOK * 512; g.sAi = 0; g.ldA = 512;
      g.B = w1T + (long long)j * 2048 * 512; g.sBe = 6LL * 2048 * 512; g.sBi = 0; g.ldB = 512;
      g.C = f1; g.sCe = (long long)TOK * 2048; g.sCi = 0; g.ldC = 2048;
      g.M = TOK; g.N = 2048; g.K = 512; g.iPerE = 1;
      gemm_kernel<M_RELU, false, 128, 128><<<dim3(32, 16, 2), 256, 0, stream>>>(g);
    }
    {  // T1 = F1 @ W2 (fp32 out)
      GemmArgs g = {};
      g.A = f1; g.sAe = (long long)TOK * 2048; g.sAi = 0; g.ldA = 2048;
      g.B = w2T + (long long)j * 512 * 2048; g.sBe = 6LL * 512 * 2048; g.sBi = 0; g.ldB = 2048;
      g.Cf = t1f; g.sCe = (long long)TOK * 512; g.sCi = 0; g.ldC = 512;
      g.M = TOK; g.N = 512; g.K = 2048; g.iPerE = 1;
      gemm_kernel<M_F32, false, 64, 128><<<dim3(64, 4, 2), 256, 0, stream>>>(g);
    }
    // state = LN(H + ff); last layer writes final output directly (concat + reverse fused)
    ln_kernel<<<dim3(1024, 2), 256, 0, stream>>>(Sf, t1f, ln_a, ln_b, (j * 4 + 2) * 512, Sb, Sf,
                                                 (j == 5) ? 1 : 0, out);
  }
}

// Round 5
// 1096.983 us; speedup vs baseline: 1.1944x; 1.0715x over previous
//
#include <hip/hip_runtime.h>

typedef __bf16 bf16;
typedef __bf16 bf16x8 __attribute__((ext_vector_type(8)));
typedef __bf16 bf16x4 __attribute__((ext_vector_type(4)));
typedef __bf16 bf16x2 __attribute__((ext_vector_type(2)));
typedef float f32x4 __attribute__((ext_vector_type(4)));

typedef __attribute__((address_space(3))) void lds_void_t;
typedef const __attribute__((address_space(1))) void gbl_void_t;

#define TOK 4096
#define KBROWS 5120

enum { M_BF16 = 0, M_F32 = 1, M_RELU = 2, M_QKV = 3, M_SCOREXP = 4, M_PV = 5 };

struct GemmArgs {
  const bf16* A; long long sAe, sAi; int ldA;
  const bf16* B; long long sBe, sBi; int ldB;
  const bf16* B2; long long sB2e; int ldB2;
  bf16* C; float* Cf; long long sCe, sCi; int ldC;
  int M, N, K, iPerE;
  bf16 *quv, *kbuf, *vt;
  const float *uvA, *uvB;
  float scale;
};

// ---------------- GEMM: C = A @ B^T, A (MxK) row-major, B (NxK) row-major ----------------
// Staging via global_load_lds; lane (8r+c) fetches chunk c^r -> XOR-swizzled LDS, frag reads
// sw=(4s+quad)^l7 are 0-bank-conflict. M_SCOREXP: epilogue exp (bounded logits, mask->0);
// fully-masked blocks (tn+TN<=T, T mult of 512) early-return — P pre-zeroed once in setup.
// M_PV: skips K<kstart (those P cols are exact zeros); row-sum l computed in-loop, /l in epi;
// bf16 output (residual stream is bf16 — see ln_kernel).
// M_QKV region 2 (vt transposed scatter): routed through LDS with involution swizzle.
template<int MODE, bool SPLITB, int TM, int TN>
__global__ __launch_bounds__(256, 4)
void gemm_kernel(GemmArgs g) {
  constexpr int FA = TM / 32, FB = TN / 32;
  int z = blockIdx.z;
  int e = z / g.iPerE;
  int i = z % g.iPerE;

  int tm = blockIdx.x * TM;
  int tn = blockIdx.y * TN;

  if constexpr (MODE == M_SCOREXP) {
    int T = 1024 - ((i < 2 ? i : 2) << 9);
    if (tn + TN <= T) return;   // fully masked tile: P already zero (setup), PV skips it
  }

  const bf16* A = g.A + e * g.sAe + i * g.sAi;
  const bf16* B = g.B + e * g.sBe + i * g.sBi;
  const bf16* B2 = nullptr;
  if constexpr (SPLITB) B2 = g.B2 + e * g.sB2e;

  __shared__ uint4 smem[TM * 8 + TN * 8];
  uint4* As4 = smem;
  uint4* Bs4 = smem + TM * 8;
  __shared__ float ls[MODE == M_PV ? TM : 1];
  bf16* As_lds = (bf16*)As4;
  bf16* Bs_lds = (bf16*)Bs4;

  int tid = threadIdx.x;
  int wave = tid >> 6, lane = tid & 63;
  int wm = (wave >> 1) * (TM / 2), wn = (wave & 1) * (TN / 2);
  int quad = lane >> 4, l15 = lane & 15;
  int l7 = l15 & 7;
  int l8r = lane >> 3, l8c = lane & 7;
  int fc = l8c ^ l8r;

  f32x4 acc[FA][FB] = {};
  float lreg[FA];
#pragma unroll
  for (int t = 0; t < FA; ++t) lreg[t] = 0.f;

  int kstart = 0;
  if constexpr (MODE == M_PV) kstart = (i < 2) ? (2 - i) << 9 : 0;  // P cols < kstart are 0

  for (int k0 = kstart; k0 < g.K; k0 += 64) {
#pragma unroll
    for (int ii = 0; ii < FA; ++ii) {
      int rowbase = (wave * FA + ii) * 8;
      int r = rowbase + l8r;
      const bf16* gp = &A[(long long)(tm + r) * g.ldA + k0 + fc * 8];
      __builtin_amdgcn_global_load_lds((gbl_void_t*)gp, (lds_void_t*)&As_lds[rowbase * 64], 16, 0, 0);
    }
#pragma unroll
    for (int ii = 0; ii < FB; ++ii) {
      int rowbase = (wave * FB + ii) * 8;
      int r = rowbase + l8r;
      const bf16* gp;
      if constexpr (SPLITB) {
        int kk = k0 + fc * 8;
        gp = (kk < 512) ? &B[(long long)(tn + r) * g.ldB + kk]
                        : &B2[(long long)(tn + r) * g.ldB2 + (kk - 512)];
      } else {
        gp = &B[(long long)(tn + r) * g.ldB + k0 + fc * 8];
      }
      __builtin_amdgcn_global_load_lds((gbl_void_t*)gp, (lds_void_t*)&Bs_lds[rowbase * 64], 16, 0, 0);
    }
    __syncthreads();
#pragma unroll
    for (int s = 0; s < 2; ++s) {
      int sw = (s * 4 + quad) ^ l7;
      bf16x8 af[FA], bfr[FB];
#pragma unroll
      for (int t = 0; t < FA; ++t) af[t]  = ((const bf16x8*)As4)[(wm + t * 16 + l15) * 8 + sw];
#pragma unroll
      for (int t = 0; t < FB; ++t) bfr[t] = ((const bf16x8*)Bs4)[(wn + t * 16 + l15) * 8 + sw];
      if constexpr (MODE == M_PV) {
#pragma unroll
        for (int t = 0; t < FA; ++t)
#pragma unroll
          for (int q2 = 0; q2 < 8; ++q2) lreg[t] += (float)af[t][q2];
      }
#pragma unroll
      for (int a = 0; a < FA; ++a)
#pragma unroll
        for (int b = 0; b < FB; ++b)
          acc[a][b] = __builtin_amdgcn_mfma_f32_16x16x32_bf16(af[a], bfr[b], acc[a][b], 0, 0, 0);
    }
    __syncthreads();
  }

  if constexpr (MODE == M_PV) {
    // rowsum l: lane holds partial of row (wm + t*16 + l15); reduce across quads
#pragma unroll
    for (int t = 0; t < FA; ++t) {
      lreg[t] += __shfl_xor(lreg[t], 16);
      lreg[t] += __shfl_xor(lreg[t], 32);
      if (quad == 0) ls[wm + t * 16 + l15] = lreg[t];
    }
    __syncthreads();
  }

  // epilogues. C/D layout: col = lane&15, row = quad*4 + reg (m89-verified)
  if constexpr (MODE == M_QKV) {
    const float* uv = e ? g.uvB : g.uvA;
    int region = tn >> 9;   // block-uniform: TN=128 tiles never span a 512-col region
    if (region == 2) {
      // S@Wvo -> vwoT[od][1024+token]: transpose through LDS (smem free after K-loop barrier)
      bf16* sm = (bf16*)smem;   // 128x128 bf16 (requires TM==TN==128)
#pragma unroll
      for (int a = 0; a < FA; ++a) {
        int m_l = wm + a * 16 + quad * 4;
#pragma unroll
        for (int b = 0; b < FB; ++b) {
          int c_l = wn + b * 16 + l15;
          int mp = m_l ^ ((c_l & 15) << 3);
          bf16 v4[4] __attribute__((aligned(8)));
#pragma unroll
          for (int r = 0; r < 4; ++r) v4[r] = (bf16)acc[a][b][r];
          *(bf16x4*)&sm[c_l * 128 + mp] = *(const bf16x4*)v4;
        }
      }
      __syncthreads();
      int c_l = tid >> 1;
      int half = (tid & 1) * 64;
      long long vb = (long long)e * 512 * KBROWS + (long long)(tn - 1024 + c_l) * KBROWS + 1024 + tm;
#pragma unroll
      for (int u = 0; u < 8; ++u) {
        int m0 = half + u * 8;
        int mp = m0 ^ ((c_l & 15) << 3);
        *(bf16x8*)&g.vt[vb + m0] = *(const bf16x8*)&sm[c_l * 128 + mp];
      }
    } else if (region == 0) {
#pragma unroll
      for (int a = 0; a < FA; ++a) {
        int mB = tm + wm + a * 16 + quad * 4;
#pragma unroll
        for (int b = 0; b < FB; ++b) {
          int cin = tn + wn + b * 16 + l15;
          float u0 = uv[cin], v0 = uv[512 + cin];
#pragma unroll
          for (int r = 0; r < 4; ++r) {
            int m = mB + r;
            float val = acc[a][b][r];
            long long qb = (long long)e * TOK * 1024 + (long long)m * 1024;
            g.quv[qb + cin]       = (bf16)(val + u0);
            g.quv[qb + 512 + cin] = (bf16)(val + v0);
          }
        }
      }
    } else {
#pragma unroll
      for (int a = 0; a < FA; ++a) {
        int mB = tm + wm + a * 16 + quad * 4;
#pragma unroll
        for (int b = 0; b < FB; ++b) {
          int cin = (tn - 512) + wn + b * 16 + l15;
#pragma unroll
          for (int r = 0; r < 4; ++r)
            g.kbuf[(long long)e * KBROWS * 512 + (long long)(1024 + mB + r) * 512 + cin] =
                (bf16)acc[a][b][r];
        }
      }
    }
  } else if constexpr (MODE == M_SCOREXP) {
    bf16* C = g.C + e * g.sCe + i * g.sCi;
    int T = 1024 - ((i < 2 ? i : 2) << 9);   // mask cols < T
#pragma unroll
    for (int a = 0; a < FA; ++a) {
      int mB = tm + wm + a * 16 + quad * 4;
#pragma unroll
      for (int b = 0; b < FB; ++b) {
        int col = tn + wn + b * 16 + l15;
        float bias = (col < T) ? -1e9f : 0.0f;
#pragma unroll
        for (int r = 0; r < 4; ++r)
          C[(long long)(mB + r) * g.ldC + col] = (bf16)__expf(acc[a][b][r] * g.scale + bias);
      }
    }
  } else if constexpr (MODE == M_PV) {
    bf16* C = g.C + e * g.sCe + i * g.sCi;
#pragma unroll
    for (int a = 0; a < FA; ++a) {
      int lrow = wm + a * 16 + quad * 4;
      int mB = tm + lrow;
#pragma unroll
      for (int b = 0; b < FB; ++b) {
        int col = tn + wn + b * 16 + l15;
#pragma unroll
        for (int r = 0; r < 4; ++r)
          C[(long long)(mB + r) * g.ldC + col] = (bf16)(acc[a][b][r] / ls[lrow + r]);
      }
    }
  } else {
#pragma unroll
    for (int a = 0; a < FA; ++a) {
      int mB = tm + wm + a * 16 + quad * 4;
#pragma unroll
      for (int b = 0; b < FB; ++b) {
        int col = tn + wn + b * 16 + l15;
#pragma unroll
        for (int r = 0; r < 4; ++r) {
          float val = acc[a][b][r];
          if constexpr (MODE == M_RELU) val = val > 0.f ? val : 0.f;
          if constexpr (MODE == M_F32) {
            float* Cf = g.Cf + e * g.sCe + i * g.sCi;
            Cf[(long long)(mB + r) * g.ldC + col] = val;
          } else {
            bf16* C = g.C + e * g.sCe + i * g.sCi;
            C[(long long)(mB + r) * g.ldC + col] = (bf16)val;
          }
        }
      }
    }
  }
}

// ---------------- unified setup: weight prep + sinusoid + embed + zero_kv + zero_P ----------------
__device__ inline void prep_locate(int id, const float* qa, const float* qb,
                                   const float* oa, const float* ob,
                                   const float* w1a, const float* w1b,
                                   const float* w2a, const float* w2b,
                                   bf16* wqkvT, bf16* wrT, bf16* wvPlain, bf16* woT,
                                   bf16* w1T, bf16* w2T,
                                   const float*& src, bf16*& dst, int& R, int& C,
                                   int& tx, int& ty, bool& plain) {
  plain = false;
  if (id < 3072) {          // Wqkvr: 48 mats x 64 tiles
    int mat = id >> 6, tile = id & 63;
    tx = tile & 7; ty = tile >> 3;
    int e = mat / 24, rj = mat % 24, j = rj >> 2, c = rj & 3;
    src = (e ? qb : qa) + (long long)(j * 4 + c) * 262144;
    R = 512; C = 512;
    if (c < 2)        dst = wqkvT + ((long long)(e * 6 + j) * 3 + c) * 262144;
    else if (c == 2) { dst = wvPlain + (long long)(e * 6 + j) * 262144; plain = true; }
    else              dst = wrT + (long long)(e * 6 + j) * 262144;
  } else if (id < 3840) {   // Wo: 12 mats x 64 tiles
    int id2 = id - 3072; int mat = id2 >> 6, tile = id2 & 63;
    tx = tile & 7; ty = tile >> 3;
    int e = mat / 6, j = mat % 6;
    src = (e ? ob : oa) + (long long)j * 262144;
    dst = woT + (long long)mat * 262144; R = 512; C = 512;
  } else if (id < 6912) {   // W1 (512x2048): 12 mats x 256 tiles
    int id2 = id - 3840; int mat = id2 >> 8, tile = id2 & 255;
    tx = tile & 31; ty = tile >> 5;
    int e = mat / 6, j = mat % 6;
    src = (e ? w1b : w1a) + (long long)j * 512 * 2048;
    dst = w1T + (long long)mat * 512 * 2048; R = 512; C = 2048;
  } else {                  // W2 (2048x512): 12 mats x 256 tiles
    int id2 = id - 6912; int mat = id2 >> 8, tile = id2 & 255;
    tx = tile & 7; ty = tile >> 3;
    int e = mat / 6, j = mat % 6;
    src = (e ? w2b : w2a) + (long long)j * 2048 * 512;
    dst = w2T + (long long)mat * 2048 * 512; R = 2048; C = 512;
  }
}

// block-id ranges: [0,2496) prep (4 tiles each) | [2496,4032) sinusoid |
//  [4032,8128) embed (2 rows) | [8128,12224) zero_kv | [12224,14272) zero masked P regions
__global__ __launch_bounds__(256)
void setup_kernel(const float* qa, const float* qb, const float* oa, const float* ob,
                  const float* w1a, const float* w1b, const float* w2a, const float* w2b,
                  bf16* wqkvT, bf16* wrT, bf16* wvPlain, bf16* woT, bf16* w1T, bf16* w2T,
                  bf16* rb, const int* src, const float* emb, bf16* Sb,
                  bf16* kbuf, bf16* vwoT, bf16* P) {
  __shared__ bf16 t[2][64 * 68];
  int bid = blockIdx.x;
  int tid = threadIdx.x;

  if (bid < 2496) {
    // ---- weight prep: 4 adjacent col-tiles (same mat/rows; boundaries all %4==0) ----
    int id0 = bid * 4;
    const float* src_w; bf16* dst; int R, C, tx0, ty; bool plain;
    prep_locate(id0, qa, qb, oa, ob, w1a, w1b, w2a, w2b,
                wqkvT, wrT, wvPlain, woT, w1T, w2T, src_w, dst, R, C, tx0, ty, plain);
    int r0 = ty * 64;

    if (plain) {
      int c8 = (tid & 7) * 8;
      int r8 = tid >> 3;                       // 0..31
      float4 f[4][4];
#pragma unroll
      for (int p = 0; p < 4; ++p) {
        int c0 = (tx0 + p) * 64;
#pragma unroll
        for (int rep = 0; rep < 2; ++rep) {
          const float* sp = &src_w[(long long)(r0 + r8 + rep * 32) * C + c0 + c8];
          f[p][rep * 2]     = *(const float4*)sp;
          f[p][rep * 2 + 1] = *(const float4*)(sp + 4);
        }
      }
#pragma unroll
      for (int p = 0; p < 4; ++p) {
        int c0 = (tx0 + p) * 64;
#pragma unroll
        for (int rep = 0; rep < 2; ++rep) {
          float4 f0 = f[p][rep * 2], f1 = f[p][rep * 2 + 1];
          bf16 o[8] __attribute__((aligned(16))) =
            {(bf16)f0.x, (bf16)f0.y, (bf16)f0.z, (bf16)f0.w,
             (bf16)f1.x, (bf16)f1.y, (bf16)f1.z, (bf16)f1.w};
          *(bf16x8*)&dst[(long long)(r0 + r8 + rep * 32) * C + c0 + c8] = *(const bf16x8*)o;
        }
      }
    } else {
      // two pairs through the same 2-buffer LDS; pair-B loads issued during pair-A store phase
      int l15 = tid & 15;                      // src-col group
      int hi  = tid >> 4;                      // 0..15 src-row
      int cc = l15 * 4;
      int oc = tid >> 2;                       // output row (src col) 0..63
      int kk = tid & 3;                        // 16-elem chunk
      float4 fA[2][4], fB[2][4];
#pragma unroll
      for (int p = 0; p < 2; ++p) {
        int c0 = (tx0 + p) * 64;
#pragma unroll
        for (int rep = 0; rep < 4; ++rep)
          fA[p][rep] = *(const float4*)&src_w[(long long)(r0 + hi + rep * 16) * C + c0 + cc];
      }
#pragma unroll
      for (int p = 0; p < 2; ++p)
#pragma unroll
        for (int rep = 0; rep < 4; ++rep) {
          int rr = hi + rep * 16;
          float v[4] = {fA[p][rep].x, fA[p][rep].y, fA[p][rep].z, fA[p][rep].w};
#pragma unroll
          for (int i2 = 0; i2 < 4; ++i2) {
            int row = cc + i2;
            int col = rr ^ (((row >> 4) & 3) << 2);
            t[p][row * 68 + col] = (bf16)v[i2];
          }
        }
      // issue pair-B loads before the barrier: latency hides under pair-A's store phase
#pragma unroll
      for (int p = 0; p < 2; ++p) {
        int c0 = (tx0 + 2 + p) * 64;
#pragma unroll
        for (int rep = 0; rep < 4; ++rep)
          fB[p][rep] = *(const float4*)&src_w[(long long)(r0 + hi + rep * 16) * C + c0 + cc];
      }
      __syncthreads();
#pragma unroll
      for (int p = 0; p < 2; ++p) {
        int c0 = (tx0 + p) * 64;
        bf16 outv[16] __attribute__((aligned(16)));
#pragma unroll
        for (int u = 0; u < 4; ++u) {
          int col = (16 * kk + 4 * u) ^ (((oc >> 4) & 3) << 2);
          *(bf16x4*)&outv[u * 4] = *(const bf16x4*)&t[p][oc * 68 + col];
        }
        bf16* dp = &dst[(long long)(c0 + oc) * R + r0 + 16 * kk];
        *(bf16x8*)dp       = *(const bf16x8*)&outv[0];
        *(bf16x8*)(dp + 8) = *(const bf16x8*)&outv[8];
      }
      __syncthreads();
#pragma unroll
      for (int p = 0; p < 2; ++p)
#pragma unroll
        for (int rep = 0; rep < 4; ++rep) {
          int rr = hi + rep * 16;
          float v[4] = {fB[p][rep].x, fB[p][rep].y, fB[p][rep].z, fB[p][rep].w};
#pragma unroll
          for (int i2 = 0; i2 < 4; ++i2) {
            int row = cc + i2;
            int col = rr ^ (((row >> 4) & 3) << 2);
            t[p][row * 68 + col] = (bf16)v[i2];
          }
        }
      __syncthreads();
#pragma unroll
      for (int p = 0; p < 2; ++p) {
        int c0 = (tx0 + 2 + p) * 64;
        bf16 outv[16] __attribute__((aligned(16)));
#pragma unroll
        for (int u = 0; u < 4; ++u) {
          int col = (16 * kk + 4 * u) ^ (((oc >> 4) & 3) << 2);
          *(bf16x4*)&outv[u * 4] = *(const bf16x4*)&t[p][oc * 68 + col];
        }
        bf16* dp = &dst[(long long)(c0 + oc) * R + r0 + 16 * kk];
        *(bf16x8*)dp       = *(const bf16x8*)&outv[0];
        *(bf16x8*)(dp + 8) = *(const bf16x8*)&outv[8];
      }
    }
  } else if (bid < 4032) {
    // ---- sinusoid ----
    int i = bid - 2496, m = tid;
    float p = (float)(1535 - i);
    float inv = expf(-((float)(2 * m) * (1.0f / 512.0f)) * 9.210340371976184f);
    float ang = p * inv;
    bf16x2 v = {(bf16)sinf(ang), (bf16)cosf(ang)};
    *(bf16x2*)&rb[(long long)i * 512 + 2 * m] = v;
  } else if (bid < 8128) {
    // ---- embed: 2 (row,e) pairs per block (bf16 state only) ----
    int rp = (bid - 4032) * 2 + (tid >> 7);
    int e2 = rp >> 12, row = rp & 4095;
    int t2 = tid & 127;
    int tok = e2 ? src[4095 - row] : src[row];
    long long base = ((long long)e2 * TOK + row) * 512 + t2 * 4;
    float4 f = *(const float4*)&emb[(long long)tok * 512 + t2 * 4];
    bf16 o[4] __attribute__((aligned(8))) = {(bf16)f.x, (bf16)f.y, (bf16)f.z, (bf16)f.w};
    *(bf16x4*)&Sb[base] = *(const bf16x4*)o;
  } else if (bid < 12224) {
    // ---- zero_kv ----
    int idx = bid - 8128;
    int which = idx >> 11, e2 = (idx >> 10) & 1, r = idx & 1023;
    uint4 zv = {0u, 0u, 0u, 0u};
    if (which == 0) {
      if (tid < 64) ((uint4*)(kbuf + ((long long)e2 * KBROWS + r) * 512))[tid] = zv;
    } else if (r < 512) {
      if (tid < 128) ((uint4*)(vwoT + ((long long)e2 * 512 + r) * KBROWS))[tid] = zv;
    }
  } else {
    // ---- zero masked P regions (written once; SCOREXP skips these tiles every layer) ----
    int idx = bid - 12224;                 // [0, 2048)
    int e2 = idx >> 10, rr = idx & 1023;
    uint4 zv = {0u, 0u, 0u, 0u};
    long long sCe = 8LL * 512 * 1536, sCi = 512LL * 1536;
    if (rr < 512) {            // seg 0 row rr, 1024 cols = 128 uint4
      if (tid < 128) ((uint4*)(P + e2 * sCe + 0 * sCi + (long long)rr * 1536))[tid] = zv;
    } else {                   // seg 1 row rr-512, 512 cols = 64 uint4
      if (tid < 64) ((uint4*)(P + e2 * sCe + 1 * sCi + (long long)(rr - 512) * 1536))[tid] = zv;
    }
  }
}

// ---------------- residual + layernorm; bf16 residual stream ----------------
// v4: x and t read as bf16x8 (residual base == Sb value by construction; t1 branch output
// bf16 — error an order below the bf16-GEMM noise floor). 4 rows/block, 1 wave/row.
__global__ __launch_bounds__(256)
void ln_kernel(const bf16* Xb, const bf16* Tb, const float* lnA, const float* lnB,
               int gOff, bf16* OutB, int outMode, float* finalOut) {
  int wave = threadIdx.x >> 6;
  int row = blockIdx.x * 4 + wave, e = blockIdx.y;
  long long base = ((long long)e * TOK + row) * 512;
  const float* ln = e ? lnB : lnA;
  int lane = threadIdx.x & 63;
  int d0 = lane * 8;
  bf16x8 xv = *(const bf16x8*)&Xb[base + d0];
  bf16x8 tv = *(const bf16x8*)&Tb[base + d0];
  float vals[8];
#pragma unroll
  for (int k = 0; k < 8; ++k) vals[k] = (float)xv[k] + (float)tv[k];
  float s = 0.f;
#pragma unroll
  for (int k = 0; k < 8; ++k) s += vals[k];
  for (int off = 32; off; off >>= 1) s += __shfl_xor(s, off);
  float mu = s * (1.0f / 512.0f);
  float vs = 0.f;
#pragma unroll
  for (int k = 0; k < 8; ++k) { float d = vals[k] - mu; vs += d * d; }
  for (int off = 32; off; off >>= 1) vs += __shfl_xor(vs, off);
  float rstd = rsqrtf(vs * (1.0f / 512.0f) + 1e-5f);
  float4 g0 = *(const float4*)&ln[gOff + d0];
  float4 g1 = *(const float4*)&ln[gOff + d0 + 4];
  float4 b0 = *(const float4*)&ln[gOff + 512 + d0];
  float4 b1 = *(const float4*)&ln[gOff + 512 + d0 + 4];
  float gm[8] = {g0.x, g0.y, g0.z, g0.w, g1.x, g1.y, g1.z, g1.w};
  float bt[8] = {b0.x, b0.y, b0.z, b0.w, b1.x, b1.y, b1.z, b1.w};
  float y[8];
#pragma unroll
  for (int k = 0; k < 8; ++k) y[k] = (vals[k] - mu) * rstd * gm[k] + bt[k];
  if (outMode == 0) {
    bf16 ob8[8] __attribute__((aligned(16)));
#pragma unroll
    for (int k = 0; k < 8; ++k) ob8[k] = (bf16)y[k];
    *(bf16x8*)&OutB[base + d0] = *(const bf16x8*)ob8;
  } else {
    long long ob = e ? ((long long)(4095 - row) * 1024 + 512) : ((long long)row * 1024);
    float4 ya = {y[0], y[1], y[2], y[3]}, yb = {y[4], y[5], y[6], y[7]};
    *(float4*)&finalOut[ob + d0]     = ya;
    *(float4*)&finalOut[ob + d0 + 4] = yb;
  }
}

extern "C" void kernel_launch(void* const* d_in, const int* in_sizes, int n_in,
                              void* d_out, int out_size, void* d_ws, size_t ws_size,
                              hipStream_t stream) {
  const int*   src   = (const int*)d_in[0];
  const float* emb   = (const float*)d_in[2];
  const float* Wq_a  = (const float*)d_in[3];
  const float* Wo_a  = (const float*)d_in[4];
  const float* W1_a  = (const float*)d_in[5];
  const float* W2_a  = (const float*)d_in[6];
  const float* ln_a  = (const float*)d_in[7];
  const float* uv_a  = (const float*)d_in[8];
  const float* Wq_b  = (const float*)d_in[9];
  const float* Wo_b  = (const float*)d_in[10];
  const float* W1_b  = (const float*)d_in[11];
  const float* W2_b  = (const float*)d_in[12];
  const float* ln_b  = (const float*)d_in[13];
  const float* uv_b  = (const float*)d_in[14];
  float* out = (float*)d_out;

  char* w = (char*)d_ws;
  size_t off = 0;
  auto alloc = [&](long long elems, int esz) -> char* {
    char* p = w + off;
    off += (size_t)elems * esz;
    off = (off + 255) & ~(size_t)255;
    return p;
  };
  bf16* wqkvT = (bf16*)alloc(2LL * 6 * 1536 * 512, 2);  // rows: q, k, (wvo = Wv@Wo set at runtime)
  bf16* woT   = (bf16*)alloc(2LL * 6 * 512 * 512, 2);
  bf16* w1T   = (bf16*)alloc(2LL * 6 * 2048 * 512, 2);
  bf16* w2T   = (bf16*)alloc(2LL * 6 * 512 * 2048, 2);
  bf16* pk    = (bf16*)alloc(2LL * 6 * 1536 * 512, 2);
  bf16* Sb    = (bf16*)alloc(2LL * TOK * 512, 2);
  bf16* quv   = (bf16*)alloc(2LL * TOK * 1024, 2);
  bf16* kbuf  = (bf16*)alloc(2LL * KBROWS * 512, 2);
  bf16* vwoT  = (bf16*)alloc(2LL * 512 * KBROWS, 2);
  bf16* P     = (bf16*)alloc(2LL * 8 * 512 * 1536, 2);
  bf16* t1b   = (bf16*)alloc(2LL * TOK * 512, 2);
  bf16* f1    = (bf16*)alloc(2LL * TOK * 2048, 2);
  // overlays (setup-only, inside f1's region; f1 first written in layer loop):
  bf16* rb      = f1;                          // 1.5 MB
  bf16* wrT     = f1 + 1024LL * 1024;          // 6 MB at +2MB
  bf16* wvPlain = f1 + 4096LL * 1024;          // 6 MB at +8MB

  if (off > ws_size) return;

  // ---- setup (single dispatch) ----
  setup_kernel<<<14272, 256, 0, stream>>>(Wq_a, Wq_b, Wo_a, Wo_b, W1_a, W1_b, W2_a, W2_b,
                                          wqkvT, wrT, wvPlain, woT, w1T, w2T,
                                          rb, src, emb, Sb, kbuf, vwoT, P);

  {  // pk[e][j] = R @ Wr[e][j]
    GemmArgs g = {};
    g.A = rb; g.sAe = 0; g.sAi = 0; g.ldA = 512;
    g.B = wrT; g.sBe = 0; g.sBi = 512LL * 512; g.ldB = 512;
    g.C = pk; g.sCe = 0; g.sCi = 1536LL * 512; g.ldC = 512;
    g.M = 1536; g.N = 512; g.K = 512; g.iPerE = 12;
    gemm_kernel<M_BF16, false, 128, 128><<<dim3(12, 4, 12), 256, 0, stream>>>(g);
  }
  {  // wvoT[e][j][od][k] = Wvo[k][od] = sum_v Wv[k][v] Wo[v][od]  -> wqkvT slot 2
    GemmArgs g = {};
    g.A = woT; g.sAe = 6LL * 262144; g.sAi = 262144; g.ldA = 512;       // A[od][v] = Wo[v][od]
    g.B = wvPlain; g.sBe = 6LL * 262144; g.sBi = 262144; g.ldB = 512;   // B[k][v]  = Wv[k][v]
    g.C = wqkvT + 2LL * 262144; g.sCe = 18LL * 262144; g.sCi = 3LL * 262144; g.ldC = 512;
    g.M = 512; g.N = 512; g.K = 512; g.iPerE = 6;
    gemm_kernel<M_BF16, false, 128, 128><<<dim3(4, 4, 12), 256, 0, stream>>>(g);
  }

  const float scale = 0.044194173824159216f;  // 1/sqrt(512)

  for (int j = 0; j < 6; ++j) {
    {  // QKV: q+u/q+v -> quv, k -> kbuf(+1024), S@Wvo -> vwoT(+1024, transposed)
      GemmArgs g = {};
      g.A = Sb; g.sAe = (long long)TOK * 512; g.sAi = 0; g.ldA = 512;
      g.B = wqkvT + (long long)j * 1536 * 512; g.sBe = 6LL * 1536 * 512; g.sBi = 0; g.ldB = 512;
      g.M = TOK; g.N = 1536; g.K = 512; g.iPerE = 1;
      g.quv = quv; g.kbuf = kbuf; g.vt = vwoT; g.uvA = uv_a; g.uvB = uv_b;
      gemm_kernel<M_QKV, false, 128, 128><<<dim3(32, 12, 2), 256, 0, stream>>>(g);
    }
    {  // P = exp(qu@Kwin^T + qv@pk^T scaled+masked)  (no-max softmax numerator)
      GemmArgs g = {};
      g.A = quv; g.sAe = (long long)TOK * 1024; g.sAi = 512LL * 1024; g.ldA = 1024;
      g.B = kbuf; g.sBe = (long long)KBROWS * 512; g.sBi = 512LL * 512; g.ldB = 512;
      g.B2 = pk + (long long)j * 1536 * 512; g.sB2e = 6LL * 1536 * 512; g.ldB2 = 512;
      g.C = P; g.sCe = 8LL * 512 * 1536; g.sCi = 512LL * 1536; g.ldC = 1536;
      g.M = 512; g.N = 1536; g.K = 1024; g.iPerE = 8;
      g.scale = scale;
      gemm_kernel<M_SCOREXP, true, 128, 128><<<dim3(4, 12, 16), 256, 0, stream>>>(g);
    }
    {  // attn_proj = (P @ VWowin) / rowsum(P)  -> bf16 t1b
      GemmArgs g = {};
      g.A = P; g.sAe = 8LL * 512 * 1536; g.sAi = 512LL * 1536; g.ldA = 1536;
      g.B = vwoT; g.sBe = 512LL * KBROWS; g.sBi = 512; g.ldB = KBROWS;
      g.C = t1b; g.sCe = (long long)TOK * 512; g.sCi = 512LL * 512; g.ldC = 512;
      g.M = 512; g.N = 512; g.K = 1536; g.iPerE = 8;
      gemm_kernel<M_PV, false, 64, 128><<<dim3(8, 4, 16), 256, 0, stream>>>(g);
    }
    // H = LN(state + attn_out) — in-place into Sb
    ln_kernel<<<dim3(1024, 2), 256, 0, stream>>>(Sb, t1b, ln_a, ln_b, (j * 4 + 0) * 512, Sb, 0, out);
    {  // F1 = relu(H @ W1)
      GemmArgs g = {};
      g.A = Sb; g.sAe = (long long)TOK * 512; g.sAi = 0; g.ldA = 512;
      g.B = w1T + (long long)j * 2048 * 512; g.sBe = 6LL * 2048 * 512; g.sBi = 0; g.ldB = 512;
      g.C = f1; g.sCe = (long long)TOK * 2048; g.sCi = 0; g.ldC = 2048;
      g.M = TOK; g.N = 2048; g.K = 512; g.iPerE = 1;
      gemm_kernel<M_RELU, false, 128, 128><<<dim3(32, 16, 2), 256, 0, stream>>>(g);
    }
    {  // T1 = F1 @ W2 (bf16 out)
      GemmArgs g = {};
      g.A = f1; g.sAe = (long long)TOK * 2048; g.sAi = 0; g.ldA = 2048;
      g.B = w2T + (long long)j * 512 * 2048; g.sBe = 6LL * 512 * 2048; g.sBi = 0; g.ldB = 2048;
      g.C = t1b; g.sCe = (long long)TOK * 512; g.sCi = 0; g.ldC = 512;
      g.M = TOK; g.N = 512; g.K = 2048; g.iPerE = 1;
      gemm_kernel<M_BF16, false, 64, 128><<<dim3(64, 4, 2), 256, 0, stream>>>(g);
    }
    // state = LN(H + ff); last layer writes final output directly (concat + reverse fused)
    ln_kernel<<<dim3(1024, 2), 256, 0, stream>>>(Sb, t1b, ln_a, ln_b, (j * 4 + 2) * 512, Sb,
                                                 (j == 5) ? 1 : 0, out);
  }
}